// Round 7
// baseline (332.169 us; speedup 1.0000x reference)
//
#include <hip/hip_runtime.h>

// ---------------------------------------------------------------------------
// LigerFusedNeighborhoodAttention on MI355X (gfx950)
// B=2, S=8192, H=1024, NH=16, HD=64, KERNEL=7, DILATION=1, SCALE=1/8
//
// Pipeline (4 launches):
//   1. prep: cast X fp32->bf16 + transpose 4 weights + bias concat (fused)
//   2. fused QKV GEMM (16384 x 3072 x 1024): 256x256 tile, BK=64, 512 thr,
//      32x32x16 MFMA fragments, read-ahead 2-barrier schedule, counted
//      vmcnt(4), setprio, XOR-swizzled LDS, XCD-bijective swizzle
//      -> unified row-major QKV (16384 x 3072)
//   3. token-blocked wave attention: 1 wave = 4 consecutive tokens; K/V rows
//      streamed once, register-reused; all loads 64-lane x 16B contiguous
//   4. output GEMM (16384 x 1024 x 1024): same 256x256 32x32-frag schedule,
//      fp32 epilogue
// ---------------------------------------------------------------------------

typedef __bf16 bf16x8 __attribute__((ext_vector_type(8)));
typedef float f32x4 __attribute__((ext_vector_type(4)));
typedef float f32x16 __attribute__((ext_vector_type(16)));
typedef int int4v __attribute__((ext_vector_type(4)));
typedef unsigned short u16x8 __attribute__((ext_vector_type(8)));
typedef __attribute__((address_space(1))) void as1_void;
typedef __attribute__((address_space(3))) void as3_void;

__device__ __forceinline__ float bf2f(unsigned short u) {
    union { unsigned int u; float f; } c;
    c.u = ((unsigned int)u) << 16;
    return c.f;
}
__device__ __forceinline__ unsigned short f2bf(float f) {
    union { float f; unsigned int u; } c;
    c.f = f;
    unsigned int u = c.u;
    u += 0x7fffu + ((u >> 16) & 1u);   // round-to-nearest-even
    return (unsigned short)(u >> 16);
}

// ------------- prep: cast X + transpose 4 weights + concat bias ------------
__global__ __launch_bounds__(256) void prep(
    const float* __restrict__ X, const float* __restrict__ w0,
    const float* __restrict__ w1, const float* __restrict__ w2,
    const float* __restrict__ w3, const float* __restrict__ bq,
    const float* __restrict__ bk, const float* __restrict__ bv,
    unsigned short* __restrict__ Xb, unsigned short* __restrict__ t0,
    unsigned short* __restrict__ t3, float* __restrict__ biasQ) {
    __shared__ unsigned short tile[32][33];
    const int bid = blockIdx.x;
    if (bid < 16384) {
        int i = bid * 256 + threadIdx.x;
        float4 v = ((const float4*)X)[i];
        ushort4 o;
        o.x = f2bf(v.x); o.y = f2bf(v.y); o.z = f2bf(v.z); o.w = f2bf(v.w);
        ((ushort4*)Xb)[i] = o;
    } else if (bid < 20480) {
        const int t = bid - 16384;
        const int z = t >> 10;
        const int rem = t & 1023;
        const float* W = (z == 0) ? w0 : (z == 1) ? w1 : (z == 2) ? w2 : w3;
        unsigned short* Wt = (z == 3) ? t3 : t0 + (size_t)z * 1048576;
        const int c0 = (rem & 31) * 32;
        const int r0 = (rem >> 5) * 32;
        const int tx = threadIdx.x & 31;
        const int ty = threadIdx.x >> 5;
#pragma unroll
        for (int i = 0; i < 32; i += 8)
            tile[ty + i][tx] = f2bf(W[(size_t)(r0 + ty + i) * 1024 + c0 + tx]);
        __syncthreads();
#pragma unroll
        for (int i = 0; i < 32; i += 8)
            Wt[(size_t)(c0 + ty + i) * 1024 + r0 + tx] = tile[tx][ty + i];
    } else {
        int i = (bid - 20480) * 256 + threadIdx.x;
        if (i < 3072)
            biasQ[i] = (i < 1024) ? bq[i] : ((i < 2048) ? bk[i - 1024] : bv[i - 2048]);
    }
}

// -------- QKV GEMM: 256x256 tile, 32x32x16 frags, 2-barrier schedule -------
// C(M,3072) = A(M,1024)*Bt(3072,1024)^T + bias -> unified QKV (stride 3072).
// 512 threads = 8 waves (2Mx4N), per-wave 128x64 = 4 Mfrag x 2 Nfrag of
// 32x32, acc = f32x16[4][2].  LDS 128 KB: 2 dbuf x [A 32KB | B 32KB].
// Per K-tile (BK=64 = 4 ksteps of K=16, 2 barriers):
//   half1: ds_read A frags 0,1 + B frags (all ksteps) | stage A(t+1) |
//          16 MFMA (fi 0..1) | BARRIER (all B LDS reads consumed)
//   half2: ds_read A frags 2,3 | stage B(t+2)->current buf |
//          16 MFMA (fi 2..3) | vmcnt(4) | BARRIER (buffer flip)
// Fragment layout (verified m74/m101): A lane l -> row l&31, k (l>>5)*8..+8;
// C/D: col=lane&31, row=(reg&3)+8*(reg>>2)+4*(lane>>5).
__global__ __launch_bounds__(512, 2) void gemm_qkv8(
    const unsigned short* __restrict__ A, const unsigned short* __restrict__ Bt,
    const float* __restrict__ bias, unsigned short* __restrict__ Cb) {
    constexpr int K = 1024;
    constexpr int NT = 16;                     // K / 64
    __shared__ unsigned short smem[65536];     // 128 KB
    const int tid  = threadIdx.x;
    const int lane = tid & 63;
    const int wave = tid >> 6;

    // XCD-bijective swizzle (768 blocks, 768 % 8 == 0)
    const int id  = blockIdx.x;
    const int swz = (id & 7) * 96 + (id >> 3);
    const int bm  = (swz / 12) * 256;
    const int bn  = (swz % 12) * 256;
    const int wm  = (wave >> 2) * 128;
    const int wn  = (wave & 3) * 64;

    const int r0 = tid >> 3;
    const int g8 = ((lane & 7) ^ ((lane >> 3) & 7)) * 8;
    const unsigned short* srcA = A  + (size_t)(bm + r0) * K + g8;
    const unsigned short* srcB = Bt + (size_t)(bn + r0) * K + g8;

    auto stage = [&](const unsigned short* gb, int ldsByte, int kt) {
#pragma unroll
        for (int l = 0; l < 2; ++l)
            __builtin_amdgcn_global_load_lds(
                (const as1_void*)(gb + (size_t)l * 65536 + kt),   // +64 rows
                (as3_void*)((char*)smem + ldsByte + l * 8192 + tid * 16),
                16, 0, 0);
    };

    // prologue: tile0 {A0,A1,B0,B1} -> buf0; tile1 {B0,B1} -> buf1
    stage(srcA,          0,     0);
    stage(srcA + 131072, 16384, 0);
    stage(srcB,          32768, 0);
    stage(srcB + 131072, 49152, 0);
    stage(srcB,          65536 + 32768, 64);
    stage(srcB + 131072, 65536 + 49152, 64);
    asm volatile("s_waitcnt vmcnt(4)" ::: "memory");   // tile0 landed; B(1) in flight
    asm volatile("s_barrier" ::: "memory");

    // 32x32 fragment addressing
    const int r32  = lane & 31;
    const int half = lane >> 5;
    const int xr   = r32 & 7;
    int gS8[4];
#pragma unroll
    for (int s = 0; s < 4; ++s) gS8[s] = ((s * 2 + half) ^ xr) * 8;
    const int aR = (wm + r32) * 64;             // shorts, within A region
    const int bR = 16384 + (wn + r32) * 64;     // shorts, within B region

    f32x16 acc[4][2] = {};

    for (int t = 0; t < NT; ++t) {
        const int bufS  = (t & 1) << 15;           // current buf (shorts)
        const int nbufB = ((t + 1) & 1) << 16;     // next buf (bytes)
        const int cbufB = (t & 1) << 16;           // current buf (bytes)
        const int ktA = (t + 1 < NT ? t + 1 : NT - 1) * 64;
        const int ktB = (t + 2 < NT ? t + 2 : NT - 1) * 64;

        // ---- half 1: A frags 0,1 + B frags; stage A(t+1); MFMA fi=0,1 -----
        bf16x8 afL[2][4], bF[2][4];
#pragma unroll
        for (int fi = 0; fi < 2; ++fi)
#pragma unroll
            for (int s = 0; s < 4; ++s)
                afL[fi][s] = *(const bf16x8*)(smem + bufS + aR + fi * 2048 + gS8[s]);
#pragma unroll
        for (int fj = 0; fj < 2; ++fj)
#pragma unroll
            for (int s = 0; s < 4; ++s)
                bF[fj][s] = *(const bf16x8*)(smem + bufS + bR + fj * 2048 + gS8[s]);
        stage(srcA, nbufB, ktA);
        stage(srcA + 131072, nbufB + 16384, ktA);
        __builtin_amdgcn_s_setprio(1);
#pragma unroll
        for (int s = 0; s < 4; ++s)
#pragma unroll
            for (int fi = 0; fi < 2; ++fi)
#pragma unroll
                for (int fj = 0; fj < 2; ++fj)
                    acc[fi][fj] = __builtin_amdgcn_mfma_f32_32x32x16_bf16(
                        afL[fi][s], bF[fj][s], acc[fi][fj], 0, 0, 0);
        __builtin_amdgcn_s_setprio(0);
        asm volatile("s_barrier" ::: "memory");   // E_mid

        // ---- half 2: A frags 2,3; stage B(t+2); MFMA fi=2,3; vmcnt(4) -----
        bf16x8 afH[2][4];
#pragma unroll
        for (int fi = 0; fi < 2; ++fi)
#pragma unroll
            for (int s = 0; s < 4; ++s)
                afH[fi][s] = *(const bf16x8*)(smem + bufS + aR + (fi + 2) * 2048 + gS8[s]);
        stage(srcB, cbufB + 32768, ktB);
        stage(srcB + 131072, cbufB + 49152, ktB);
        __builtin_amdgcn_s_setprio(1);
#pragma unroll
        for (int s = 0; s < 4; ++s)
#pragma unroll
            for (int fi = 0; fi < 2; ++fi)
#pragma unroll
                for (int fj = 0; fj < 2; ++fj)
                    acc[fi + 2][fj] = __builtin_amdgcn_mfma_f32_32x32x16_bf16(
                        afH[fi][s], bF[fj][s], acc[fi + 2][fj], 0, 0, 0);
        __builtin_amdgcn_s_setprio(0);
        asm volatile("s_waitcnt vmcnt(4)" ::: "memory");   // tile t+1 fully landed
        asm volatile("s_barrier" ::: "memory");   // E_end
    }

    // drain all staging before reusing LDS as epilogue scratch
    asm volatile("s_waitcnt vmcnt(0) lgkmcnt(0)" ::: "memory");
    asm volatile("s_barrier" ::: "memory");

    // ------- epilogue (unified): bf16 rows, stride 3072, LDS bounce --------
    unsigned short* ep = smem + wave * 8192;   // 16 KB per wave
    const float bb0 = bias[bn + wn + r32];
    const float bb1 = bias[bn + wn + 32 + r32];
    const int rbase = 4 * half;
#pragma unroll
    for (int h = 0; h < 2; ++h) {
#pragma unroll
        for (int fl = 0; fl < 2; ++fl)
#pragma unroll
            for (int fj = 0; fj < 2; ++fj) {
                const float bvv = fj ? bb1 : bb0;
#pragma unroll
                for (int r = 0; r < 16; ++r) {
                    const int row = fl * 32 + (r & 3) + 8 * (r >> 2) + rbase;
                    ep[row * 68 + fj * 32 + r32] = f2bf(acc[h * 2 + fl][fj][r] + bvv);
                }
            }
#pragma unroll
        for (int p = 0; p < 8; ++p) {
            const int row = p * 8 + (lane >> 3);
            const int gr = lane & 7;
            int4v v = *(const int4v*)(ep + row * 68 + gr * 8);
            *(int4v*)(Cb + (size_t)(bm + wm + h * 64 + row) * 3072 + bn + wn + gr * 8) = v;
        }
    }
}

// ------ O-proj GEMM: same 256x256 32x32-frag 2-barrier schedule, fp32 ------
// C(16384,1024) = A(16384,1024)*Bt(1024,1024)^T + bias.  Grid 256 = 64x4.
__global__ __launch_bounds__(512, 2) void gemm_out8(
    const unsigned short* __restrict__ A, const unsigned short* __restrict__ Bt,
    const float* __restrict__ bias, float* __restrict__ Cf) {
    constexpr int K = 1024;
    constexpr int NT = 16;
    __shared__ unsigned short smem[65536];
    const int tid  = threadIdx.x;
    const int lane = tid & 63;
    const int wave = tid >> 6;

    // XCD-bijective swizzle (256 blocks, 256 % 8 == 0)
    const int id  = blockIdx.x;
    const int swz = (id & 7) * 32 + (id >> 3);
    const int bm  = (swz >> 2) * 256;
    const int bn  = (swz & 3) * 256;
    const int wm  = (wave >> 2) * 128;
    const int wn  = (wave & 3) * 64;

    const int r0 = tid >> 3;
    const int g8 = ((lane & 7) ^ ((lane >> 3) & 7)) * 8;
    const unsigned short* srcA = A  + (size_t)(bm + r0) * K + g8;
    const unsigned short* srcB = Bt + (size_t)(bn + r0) * K + g8;

    auto stage = [&](const unsigned short* gb, int ldsByte, int kt) {
#pragma unroll
        for (int l = 0; l < 2; ++l)
            __builtin_amdgcn_global_load_lds(
                (const as1_void*)(gb + (size_t)l * 65536 + kt),
                (as3_void*)((char*)smem + ldsByte + l * 8192 + tid * 16),
                16, 0, 0);
    };

    stage(srcA,          0,     0);
    stage(srcA + 131072, 16384, 0);
    stage(srcB,          32768, 0);
    stage(srcB + 131072, 49152, 0);
    stage(srcB,          65536 + 32768, 64);
    stage(srcB + 131072, 65536 + 49152, 64);
    asm volatile("s_waitcnt vmcnt(4)" ::: "memory");
    asm volatile("s_barrier" ::: "memory");

    const int r32  = lane & 31;
    const int half = lane >> 5;
    const int xr   = r32 & 7;
    int gS8[4];
#pragma unroll
    for (int s = 0; s < 4; ++s) gS8[s] = ((s * 2 + half) ^ xr) * 8;
    const int aR = (wm + r32) * 64;
    const int bR = 16384 + (wn + r32) * 64;

    f32x16 acc[4][2] = {};

    for (int t = 0; t < NT; ++t) {
        const int bufS  = (t & 1) << 15;
        const int nbufB = ((t + 1) & 1) << 16;
        const int cbufB = (t & 1) << 16;
        const int ktA = (t + 1 < NT ? t + 1 : NT - 1) * 64;
        const int ktB = (t + 2 < NT ? t + 2 : NT - 1) * 64;

        bf16x8 afL[2][4], bF[2][4];
#pragma unroll
        for (int fi = 0; fi < 2; ++fi)
#pragma unroll
            for (int s = 0; s < 4; ++s)
                afL[fi][s] = *(const bf16x8*)(smem + bufS + aR + fi * 2048 + gS8[s]);
#pragma unroll
        for (int fj = 0; fj < 2; ++fj)
#pragma unroll
            for (int s = 0; s < 4; ++s)
                bF[fj][s] = *(const bf16x8*)(smem + bufS + bR + fj * 2048 + gS8[s]);
        stage(srcA, nbufB, ktA);
        stage(srcA + 131072, nbufB + 16384, ktA);
        __builtin_amdgcn_s_setprio(1);
#pragma unroll
        for (int s = 0; s < 4; ++s)
#pragma unroll
            for (int fi = 0; fi < 2; ++fi)
#pragma unroll
                for (int fj = 0; fj < 2; ++fj)
                    acc[fi][fj] = __builtin_amdgcn_mfma_f32_32x32x16_bf16(
                        afL[fi][s], bF[fj][s], acc[fi][fj], 0, 0, 0);
        __builtin_amdgcn_s_setprio(0);
        asm volatile("s_barrier" ::: "memory");

        bf16x8 afH[2][4];
#pragma unroll
        for (int fi = 0; fi < 2; ++fi)
#pragma unroll
            for (int s = 0; s < 4; ++s)
                afH[fi][s] = *(const bf16x8*)(smem + bufS + aR + (fi + 2) * 2048 + gS8[s]);
        stage(srcB, cbufB + 32768, ktB);
        stage(srcB + 131072, cbufB + 49152, ktB);
        __builtin_amdgcn_s_setprio(1);
#pragma unroll
        for (int s = 0; s < 4; ++s)
#pragma unroll
            for (int fi = 0; fi < 2; ++fi)
#pragma unroll
                for (int fj = 0; fj < 2; ++fj)
                    acc[fi + 2][fj] = __builtin_amdgcn_mfma_f32_32x32x16_bf16(
                        afH[fi][s], bF[fj][s], acc[fi + 2][fj], 0, 0, 0);
        __builtin_amdgcn_s_setprio(0);
        asm volatile("s_waitcnt vmcnt(4)" ::: "memory");
        asm volatile("s_barrier" ::: "memory");
    }

    asm volatile("s_waitcnt vmcnt(0) lgkmcnt(0)" ::: "memory");
    asm volatile("s_barrier" ::: "memory");

    // ---- fp32 epilogue: 32-row quarters (frag fi = hh), stride-68 bounce --
    float* epf = (float*)((char*)smem + wave * 16384);   // 16 KB per wave
    const float bb0 = bias[bn + wn + r32];
    const float bb1 = bias[bn + wn + 32 + r32];
    const int rbase = 4 * half;
#pragma unroll
    for (int hh = 0; hh < 4; ++hh) {
#pragma unroll
        for (int fj = 0; fj < 2; ++fj) {
            const float bvv = fj ? bb1 : bb0;
#pragma unroll
            for (int r = 0; r < 16; ++r) {
                const int row = (r & 3) + 8 * (r >> 2) + rbase;
                epf[row * 68 + fj * 32 + r32] = acc[hh][fj][r] + bvv;
            }
        }
#pragma unroll
        for (int p = 0; p < 8; ++p) {
            const int row = p * 4 + (lane >> 4);
            const int ch = lane & 15;
            f32x4 v = *(const f32x4*)(epf + row * 68 + ch * 4);
            *(f32x4*)(Cf + (size_t)(bm + wm + hh * 32 + row) * 1024 + bn + wn + ch * 4) = v;
        }
    }
}

// ----------------- token-blocked wave attention (CHUNK = 4) ----------------
// QKV rows: (16384, 3072) bf16 = [q(1024) k(1024) v(1024)].
// 1 wave = 4 consecutive tokens; K/V rows s0-3..s0+6 streamed once each.
__global__ __launch_bounds__(256) void attn_wave4(
    const unsigned short* __restrict__ QKV, unsigned short* __restrict__ out) {
    const int lane = threadIdx.x & 63;
    const int wv   = threadIdx.x >> 6;
    const int id   = blockIdx.x;
    const int swz  = (id & 7) * 128 + (id >> 3);
    const int tok0 = swz * 16 + wv * 4;
    const int s0   = tok0 & 8191;
    const int bb   = tok0 - s0;
    const int le8  = lane * 8;

    const float NEG = -__builtin_inff();

    u16x8 qa[4][2];
#pragma unroll
    for (int t = 0; t < 4; ++t) {
        const size_t rq = (size_t)(tok0 + t) * 3072;
        qa[t][0] = *(const u16x8*)(QKV + rq + le8);
        qa[t][1] = *(const u16x8*)(QKV + rq + 512 + le8);
    }

    float sc0[4][7], sc1[4][7];
#pragma unroll
    for (int ri = 0; ri < 10; ++ri) {
        const int ks = s0 + ri - 3;
        const bool okr = (ks >= 0) & (ks < 8192);
        const int kc = ks < 0 ? 0 : (ks > 8191 ? 8191 : ks);
        const size_t kb = (size_t)(bb + kc) * 3072 + 1024;
        u16x8 k0 = *(const u16x8*)(QKV + kb + le8);
        u16x8 k1 = *(const u16x8*)(QKV + kb + 512 + le8);
#pragma unroll
        for (int t = 0; t < 4; ++t) {
            const int j = ri - t;
            if (j >= 0 && j < 7) {
                float d0 = 0.f, d1 = 0.f;
#pragma unroll
                for (int e = 0; e < 8; ++e) {
                    d0 += bf2f(qa[t][0][e]) * bf2f(k0[e]);
                    d1 += bf2f(qa[t][1][e]) * bf2f(k1[e]);
                }
#pragma unroll
                for (int off = 1; off <= 4; off <<= 1) {
                    d0 += __shfl_xor(d0, off);
                    d1 += __shfl_xor(d1, off);
                }
                sc0[t][j] = okr ? d0 * 0.125f : NEG;
                sc1[t][j] = okr ? d1 * 0.125f : NEG;
            }
        }
    }

    float w0[4][7], w1[4][7];
#pragma unroll
    for (int t = 0; t < 4; ++t) {
        float mx0 = sc0[t][0], mx1 = sc1[t][0];
#pragma unroll
        for (int j = 1; j < 7; ++j) { mx0 = fmaxf(mx0, sc0[t][j]); mx1 = fmaxf(mx1, sc1[t][j]); }
        float s0s = 0.f, s1s = 0.f;
#pragma unroll
        for (int j = 0; j < 7; ++j) {
            w0[t][j] = __builtin_amdgcn_exp2f((sc0[t][j] - mx0) * 1.44269504f);
            w1[t][j] = __builtin_amdgcn_exp2f((sc1[t][j] - mx1) * 1.44269504f);
            s0s += w0[t][j]; s1s += w1[t][j];
        }
        const float i0 = __builtin_amdgcn_rcpf(s0s);
        const float i1 = __builtin_amdgcn_rcpf(s1s);
#pragma unroll
        for (int j = 0; j < 7; ++j) { w0[t][j] *= i0; w1[t][j] *= i1; }
    }

    float o0[4][8] = {}, o1[4][8] = {};
#pragma unroll
    for (int ri = 0; ri < 10; ++ri) {
        const int ks = s0 + ri - 3;
        const int kc = ks < 0 ? 0 : (ks > 8191 ? 8191 : ks);
        const size_t vb = (size_t)(bb + kc) * 3072 + 2048;
        u16x8 v0 = *(const u16x8*)(QKV + vb + le8);
        u16x8 v1 = *(const u16x8*)(QKV + vb + 512 + le8);
        float vf0[8], vf1[8];
#pragma unroll
        for (int e = 0; e < 8; ++e) { vf0[e] = bf2f(v0[e]); vf1[e] = bf2f(v1[e]); }
#pragma unroll
        for (int t = 0; t < 4; ++t) {
            const int j = ri - t;
            if (j >= 0 && j < 7) {
#pragma unroll
                for (int e = 0; e < 8; ++e) {
                    o0[t][e] += w0[t][j] * vf0[e];
                    o1[t][e] += w1[t][j] * vf1[e];
                }
            }
        }
    }

#pragma unroll
    for (int t = 0; t < 4; ++t) {
        const size_t dst = (size_t)(tok0 + t) * 1024;
        u16x8 a, b2;
#pragma unroll
        for (int e = 0; e < 8; ++e) { a[e] = f2bf(o0[t][e]); b2[e] = f2bf(o1[t][e]); }
        *(u16x8*)(out + dst + le8) = a;
        *(u16x8*)(out + dst + 512 + le8) = b2;
    }
}

// ------------------------------- launch ------------------------------------
extern "C" void kernel_launch(void* const* d_in, const int* in_sizes, int n_in,
                              void* d_out, int out_size, void* d_ws, size_t ws_size,
                              hipStream_t stream) {
    (void)in_sizes; (void)n_in; (void)out_size; (void)ws_size;
    const float* X  = (const float*)d_in[0];
    const float* wq = (const float*)d_in[1];
    const float* bq = (const float*)d_in[2];
    const float* wk = (const float*)d_in[3];
    const float* bk = (const float*)d_in[4];
    const float* wv = (const float*)d_in[5];
    const float* bv = (const float*)d_in[6];
    const float* wo = (const float*)d_in[7];
    const float* bo = (const float*)d_in[8];
    float* out = (float*)d_out;

    char* ws = (char*)d_ws;
    unsigned short* Xb    = (unsigned short*)(ws);                 // 32 MB
    unsigned short* WtQKV = (unsigned short*)(ws + 33554432);      // 6 MB
    unsigned short* WtO   = (unsigned short*)(ws + 39845888);      // 2 MB
    unsigned short* QKV   = (unsigned short*)(ws + 41943040);      // 96 MB
    unsigned short* AttnO = (unsigned short*)(ws + 142606336);     // 32 MB
    float*          biasQ = (float*)(ws + 176160768);              // 12 KB

    prep<<<20492, 256, 0, stream>>>(X, wq, wk, wv, wo, bq, bk, bv,
                                    Xb, WtQKV, WtO, biasQ);

    // QKV: M=16384, N=3072, K=1024 -> unified QKV rows (256x256 tiles)
    gemm_qkv8<<<768, 512, 0, stream>>>(Xb, WtQKV, biasQ, QKV);

    // attention: 16384 tokens / 4 per wave = 4096 waves = 1024 blocks
    attn_wave4<<<1024, 256, 0, stream>>>(QKV, AttnO);

    // O-proj: M=16384, N=1024, K=1024, fp32 out (256x256 tiles, 256 blocks)
    gemm_out8<<<256, 512, 0, stream>>>(AttnO, WtO, bo, out);
}

// Round 8
// 317.355 us; speedup vs baseline: 1.0467x; 1.0467x over previous
//
#include <hip/hip_runtime.h>

// ---------------------------------------------------------------------------
// LigerFusedNeighborhoodAttention on MI355X (gfx950)
// B=2, S=8192, H=1024, NH=16, HD=64, KERNEL=7, DILATION=1, SCALE=1/8
//
// Pipeline (4 launches):
//   1. prep: cast X fp32->bf16 + transpose 4 weights + bias concat (fused)
//   2. fused QKV GEMM (16384 x 3072 x 1024): 256x256 tile, BK=64, 512 thr,
//      16x16x32 MFMA, 2-barrier schedule + CROSS-TILE B-operand register
//      preload (B' read after vmcnt(4) overlaps MFMA half2), counted vmcnt,
//      setprio, XOR-swizzled LDS, XCD-bijective swizzle
//      -> unified row-major QKV (16384 x 3072)
//   3. token-blocked wave attention: 1 wave = 4 consecutive tokens; K/V rows
//      streamed once, register-reused; all loads 64-lane x 16B contiguous
//   4. output GEMM (16384 x 1024 x 1024): 256x256 2-barrier schedule, fp32
//      epilogue (round-6 verified version, unchanged)
// ---------------------------------------------------------------------------

typedef __bf16 bf16x8 __attribute__((ext_vector_type(8)));
typedef float f32x4 __attribute__((ext_vector_type(4)));
typedef int int4v __attribute__((ext_vector_type(4)));
typedef unsigned short u16x8 __attribute__((ext_vector_type(8)));
typedef __attribute__((address_space(1))) void as1_void;
typedef __attribute__((address_space(3))) void as3_void;

__device__ __forceinline__ float bf2f(unsigned short u) {
    union { unsigned int u; float f; } c;
    c.u = ((unsigned int)u) << 16;
    return c.f;
}
__device__ __forceinline__ unsigned short f2bf(float f) {
    union { float f; unsigned int u; } c;
    c.f = f;
    unsigned int u = c.u;
    u += 0x7fffu + ((u >> 16) & 1u);   // round-to-nearest-even
    return (unsigned short)(u >> 16);
}

// ------------- prep: cast X + transpose 4 weights + concat bias ------------
__global__ __launch_bounds__(256) void prep(
    const float* __restrict__ X, const float* __restrict__ w0,
    const float* __restrict__ w1, const float* __restrict__ w2,
    const float* __restrict__ w3, const float* __restrict__ bq,
    const float* __restrict__ bk, const float* __restrict__ bv,
    unsigned short* __restrict__ Xb, unsigned short* __restrict__ t0,
    unsigned short* __restrict__ t3, float* __restrict__ biasQ) {
    __shared__ unsigned short tile[32][33];
    const int bid = blockIdx.x;
    if (bid < 16384) {
        int i = bid * 256 + threadIdx.x;
        float4 v = ((const float4*)X)[i];
        ushort4 o;
        o.x = f2bf(v.x); o.y = f2bf(v.y); o.z = f2bf(v.z); o.w = f2bf(v.w);
        ((ushort4*)Xb)[i] = o;
    } else if (bid < 20480) {
        const int t = bid - 16384;
        const int z = t >> 10;
        const int rem = t & 1023;
        const float* W = (z == 0) ? w0 : (z == 1) ? w1 : (z == 2) ? w2 : w3;
        unsigned short* Wt = (z == 3) ? t3 : t0 + (size_t)z * 1048576;
        const int c0 = (rem & 31) * 32;
        const int r0 = (rem >> 5) * 32;
        const int tx = threadIdx.x & 31;
        const int ty = threadIdx.x >> 5;
#pragma unroll
        for (int i = 0; i < 32; i += 8)
            tile[ty + i][tx] = f2bf(W[(size_t)(r0 + ty + i) * 1024 + c0 + tx]);
        __syncthreads();
#pragma unroll
        for (int i = 0; i < 32; i += 8)
            Wt[(size_t)(c0 + ty + i) * 1024 + r0 + tx] = tile[tx][ty + i];
    } else {
        int i = (bid - 20480) * 256 + threadIdx.x;
        if (i < 3072)
            biasQ[i] = (i < 1024) ? bq[i] : ((i < 2048) ? bk[i - 1024] : bv[i - 2048]);
    }
}

// -------- QKV GEMM: 256x256, 2-barrier schedule + cross-tile B preload -----
// C(M,3072) = A(M,1024)*Bt(3072,1024)^T + bias -> unified QKV (stride 3072).
// 512 threads = 8 waves (2Mx4N), per-wave 128x64 = acc[8][4].
// LDS 128 KB: 2 dbuf x [A 32KB | B 32KB].  K=1024, BK=64, NT=16.
// Per K-tile:
//   half1: ds_read afL+afH (A of tile t) | stage A(t+1)->other buf |
//          MFMA Q1,Q2 (B operands PRELOADED last tile) | BARRIER
//   half2: stage B(t+2)->current buf | vmcnt(4) (=> A(t+1),B(t+1) landed) |
//          ds_read B(t+1) operands into ping-pong regs (overlaps MFMA) |
//          MFMA Q3,Q4 | BARRIER
// Hazards: B' reads target next-buf B region, next overwritten by B(t+3)
// after E_mid(t+1) -- consumed by then.  vmcnt: 12 outstanding at wait point,
// vmcnt(4) retires B(t+1)+A(t+1), leaves B(t+2).  Last-iter preload reads
// dead-but-valid LDS.  Ping-pong reg sets via 2-tile unroll (no reg copies).
__global__ __launch_bounds__(512, 2) void gemm_qkv8(
    const unsigned short* __restrict__ A, const unsigned short* __restrict__ Bt,
    const float* __restrict__ bias, unsigned short* __restrict__ Cb) {
    constexpr int K = 1024;
    constexpr int NT = 16;                     // K / 64
    __shared__ unsigned short smem[65536];     // 128 KB
    const int tid  = threadIdx.x;
    const int lane = tid & 63;
    const int wave = tid >> 6;
    const int quad = lane >> 4;
    const int mr   = lane & 15;

    // XCD-bijective swizzle (768 blocks, 768 % 8 == 0)
    const int id  = blockIdx.x;
    const int swz = (id & 7) * 96 + (id >> 3);
    const int bm  = (swz / 12) * 256;
    const int bn  = (swz % 12) * 256;
    const int wm  = (wave >> 2) * 128;
    const int wn  = (wave & 3) * 64;

    const int r0 = tid >> 3;
    const int g8 = ((lane & 7) ^ ((lane >> 3) & 7)) * 8;
    const unsigned short* srcA = A  + (size_t)(bm + r0) * K + g8;
    const unsigned short* srcB = Bt + (size_t)(bn + r0) * K + g8;

    auto stage = [&](const unsigned short* gb, int ldsByte, int kt) {
#pragma unroll
        for (int l = 0; l < 2; ++l)
            __builtin_amdgcn_global_load_lds(
                (const as1_void*)(gb + (size_t)l * 65536 + kt),   // +64 rows
                (as3_void*)((char*)smem + ldsByte + l * 8192 + tid * 16),
                16, 0, 0);
    };

    // prologue: tile0 {A0,A1,B0,B1} -> buf0; tile1 {B0,B1} -> buf1
    stage(srcA,          0,     0);
    stage(srcA + 131072, 16384, 0);
    stage(srcB,          32768, 0);
    stage(srcB + 131072, 49152, 0);
    stage(srcB,          65536 + 32768, 64);
    stage(srcB + 131072, 65536 + 49152, 64);
    asm volatile("s_waitcnt vmcnt(4)" ::: "memory");   // tile0 landed; B(1) in flight
    asm volatile("s_barrier" ::: "memory");

    const int aRow = (wm + mr) * 64;            // shorts, within A region
    const int bRow = 16384 + (wn + mr) * 64;    // shorts, within B region
    const int c8_0 = ((0 * 4 + quad) ^ (mr & 7)) * 8;
    const int c8_1 = ((1 * 4 + quad) ^ (mr & 7)) * 8;

    f32x4 acc[8][4] = {};
    bf16x8 bA0[2][2], bB0[2][2], bA1[2][2], bB1[2][2];

    // preload tile0 B operands (buf0)
#pragma unroll
    for (int j = 0; j < 2; ++j) {
        bA0[j][0] = *(const bf16x8*)(smem + bRow + j * 1024 + c8_0);
        bA0[j][1] = *(const bf16x8*)(smem + bRow + j * 1024 + c8_1);
        bB0[j][0] = *(const bf16x8*)(smem + bRow + (j + 2) * 1024 + c8_0);
        bB0[j][1] = *(const bf16x8*)(smem + bRow + (j + 2) * 1024 + c8_1);
    }

    auto tile_body = [&](int t, bf16x8 (&cA)[2][2], bf16x8 (&cB)[2][2],
                         bf16x8 (&nA)[2][2], bf16x8 (&nB)[2][2]) {
        const int bufS  = (t & 1) << 15;           // current buf (shorts)
        const int nbufS = ((t + 1) & 1) << 15;     // next buf (shorts)
        const int nbufB = ((t + 1) & 1) << 16;     // next buf (bytes)
        const int cbufB = (t & 1) << 16;           // current buf (bytes)
        const int ktA = (t + 1 < NT ? t + 1 : NT - 1) * 64;
        const int ktB = (t + 2 < NT ? t + 2 : NT - 1) * 64;

        // ---- half 1: A reads (both halves); stage A(t+1); MFMA Q1,Q2 ------
        bf16x8 afL[4][2], afH[4][2];
#pragma unroll
        for (int i = 0; i < 4; ++i) {
            afL[i][0] = *(const bf16x8*)(smem + bufS + aRow + i * 1024 + c8_0);
            afL[i][1] = *(const bf16x8*)(smem + bufS + aRow + i * 1024 + c8_1);
        }
#pragma unroll
        for (int i = 0; i < 4; ++i) {
            afH[i][0] = *(const bf16x8*)(smem + bufS + aRow + (i + 4) * 1024 + c8_0);
            afH[i][1] = *(const bf16x8*)(smem + bufS + aRow + (i + 4) * 1024 + c8_1);
        }
        stage(srcA, nbufB, ktA);
        stage(srcA + 131072, nbufB + 16384, ktA);
        __builtin_amdgcn_s_setprio(1);
#pragma unroll
        for (int i = 0; i < 4; ++i)
#pragma unroll
            for (int j = 0; j < 2; ++j) {
                acc[i][j] = __builtin_amdgcn_mfma_f32_16x16x32_bf16(afL[i][0], cA[j][0], acc[i][j], 0, 0, 0);
                acc[i][j] = __builtin_amdgcn_mfma_f32_16x16x32_bf16(afL[i][1], cA[j][1], acc[i][j], 0, 0, 0);
            }
#pragma unroll
        for (int i = 0; i < 4; ++i)
#pragma unroll
            for (int j = 0; j < 2; ++j) {
                acc[i][j + 2] = __builtin_amdgcn_mfma_f32_16x16x32_bf16(afL[i][0], cB[j][0], acc[i][j + 2], 0, 0, 0);
                acc[i][j + 2] = __builtin_amdgcn_mfma_f32_16x16x32_bf16(afL[i][1], cB[j][1], acc[i][j + 2], 0, 0, 0);
            }
        __builtin_amdgcn_s_setprio(0);
        asm volatile("s_barrier" ::: "memory");   // E_mid

        // ---- half 2: stage B(t+2); vmcnt(4); preload B(t+1); MFMA Q3,Q4 ---
        stage(srcB, cbufB + 32768, ktB);
        stage(srcB + 131072, cbufB + 49152, ktB);
        asm volatile("s_waitcnt vmcnt(4)" ::: "memory");   // A(t+1),B(t+1) landed
#pragma unroll
        for (int j = 0; j < 2; ++j) {
            nA[j][0] = *(const bf16x8*)(smem + nbufS + bRow + j * 1024 + c8_0);
            nA[j][1] = *(const bf16x8*)(smem + nbufS + bRow + j * 1024 + c8_1);
            nB[j][0] = *(const bf16x8*)(smem + nbufS + bRow + (j + 2) * 1024 + c8_0);
            nB[j][1] = *(const bf16x8*)(smem + nbufS + bRow + (j + 2) * 1024 + c8_1);
        }
        __builtin_amdgcn_s_setprio(1);
#pragma unroll
        for (int i = 0; i < 4; ++i)
#pragma unroll
            for (int j = 0; j < 2; ++j) {
                acc[i + 4][j + 2] = __builtin_amdgcn_mfma_f32_16x16x32_bf16(afH[i][0], cB[j][0], acc[i + 4][j + 2], 0, 0, 0);
                acc[i + 4][j + 2] = __builtin_amdgcn_mfma_f32_16x16x32_bf16(afH[i][1], cB[j][1], acc[i + 4][j + 2], 0, 0, 0);
            }
#pragma unroll
        for (int i = 0; i < 4; ++i)
#pragma unroll
            for (int j = 0; j < 2; ++j) {
                acc[i + 4][j] = __builtin_amdgcn_mfma_f32_16x16x32_bf16(afH[i][0], cA[j][0], acc[i + 4][j], 0, 0, 0);
                acc[i + 4][j] = __builtin_amdgcn_mfma_f32_16x16x32_bf16(afH[i][1], cA[j][1], acc[i + 4][j], 0, 0, 0);
            }
        __builtin_amdgcn_s_setprio(0);
        asm volatile("s_barrier" ::: "memory");   // E_end
    };

    for (int tt = 0; tt < NT; tt += 2) {
        tile_body(tt,     bA0, bB0, bA1, bB1);
        tile_body(tt + 1, bA1, bB1, bA0, bB0);
    }

    // drain all staging before reusing LDS as epilogue scratch
    asm volatile("s_waitcnt vmcnt(0) lgkmcnt(0)" ::: "memory");
    asm volatile("s_barrier" ::: "memory");

    // ------- epilogue (unified): bf16 rows, stride 3072, LDS bounce --------
    unsigned short* ep = smem + wave * 8192;   // 16 KB per wave
#pragma unroll
    for (int h = 0; h < 2; ++h) {
#pragma unroll
        for (int j = 0; j < 4; ++j) {
            const float bvv = bias[bn + wn + j * 16 + mr];
#pragma unroll
            for (int i = 0; i < 4; ++i)
#pragma unroll
                for (int r = 0; r < 4; ++r)
                    ep[(i * 16 + quad * 4 + r) * 68 + j * 16 + mr] =
                        f2bf(acc[h * 4 + i][j][r] + bvv);
        }
#pragma unroll
        for (int p = 0; p < 8; ++p) {
            const int row = p * 8 + (lane >> 3);
            const int gr = lane & 7;
            int4v v = *(const int4v*)(ep + row * 68 + gr * 8);
            *(int4v*)(Cb + (size_t)(bm + wm + h * 64 + row) * 3072 + bn + wn + gr * 8) = v;
        }
    }
}

// ------------- O-proj GEMM: round-6 256x256 2-barrier schedule, fp32 -------
// C(16384,1024) = A(16384,1024)*Bt(1024,1024)^T + bias.  Grid 256 = 64x4.
__global__ __launch_bounds__(512, 2) void gemm_out8(
    const unsigned short* __restrict__ A, const unsigned short* __restrict__ Bt,
    const float* __restrict__ bias, float* __restrict__ Cf) {
    constexpr int K = 1024;
    constexpr int NT = 16;
    __shared__ unsigned short smem[65536];
    const int tid  = threadIdx.x;
    const int lane = tid & 63;
    const int wave = tid >> 6;
    const int quad = lane >> 4;
    const int mr   = lane & 15;

    // XCD-bijective swizzle (256 blocks, 256 % 8 == 0)
    const int id  = blockIdx.x;
    const int swz = (id & 7) * 32 + (id >> 3);
    const int bm  = (swz >> 2) * 256;
    const int bn  = (swz & 3) * 256;
    const int wm  = (wave >> 2) * 128;
    const int wn  = (wave & 3) * 64;

    const int r0 = tid >> 3;
    const int g8 = ((lane & 7) ^ ((lane >> 3) & 7)) * 8;
    const unsigned short* srcA = A  + (size_t)(bm + r0) * K + g8;
    const unsigned short* srcB = Bt + (size_t)(bn + r0) * K + g8;

    auto stage = [&](const unsigned short* gb, int ldsByte, int kt) {
#pragma unroll
        for (int l = 0; l < 2; ++l)
            __builtin_amdgcn_global_load_lds(
                (const as1_void*)(gb + (size_t)l * 65536 + kt),
                (as3_void*)((char*)smem + ldsByte + l * 8192 + tid * 16),
                16, 0, 0);
    };

    stage(srcA,          0,     0);
    stage(srcA + 131072, 16384, 0);
    stage(srcB,          32768, 0);
    stage(srcB + 131072, 49152, 0);
    stage(srcB,          65536 + 32768, 64);
    stage(srcB + 131072, 65536 + 49152, 64);
    asm volatile("s_waitcnt vmcnt(4)" ::: "memory");
    asm volatile("s_barrier" ::: "memory");

    const int aRow = (wm + mr) * 64;
    const int bRow = 16384 + (wn + mr) * 64;
    const int c8_0 = ((0 * 4 + quad) ^ (mr & 7)) * 8;
    const int c8_1 = ((1 * 4 + quad) ^ (mr & 7)) * 8;

    f32x4 acc[8][4] = {};

    for (int t = 0; t < NT; ++t) {
        const int bufS  = (t & 1) << 15;
        const int nbufB = ((t + 1) & 1) << 16;
        const int cbufB = (t & 1) << 16;
        const int ktA = (t + 1 < NT ? t + 1 : NT - 1) * 64;
        const int ktB = (t + 2 < NT ? t + 2 : NT - 1) * 64;

        bf16x8 afL[4][2], bA[2][2], bB[2][2];
#pragma unroll
        for (int i = 0; i < 4; ++i) {
            afL[i][0] = *(const bf16x8*)(smem + bufS + aRow + i * 1024 + c8_0);
            afL[i][1] = *(const bf16x8*)(smem + bufS + aRow + i * 1024 + c8_1);
        }
#pragma unroll
        for (int j = 0; j < 2; ++j) {
            bA[j][0] = *(const bf16x8*)(smem + bufS + bRow + j * 1024 + c8_0);
            bA[j][1] = *(const bf16x8*)(smem + bufS + bRow + j * 1024 + c8_1);
        }
#pragma unroll
        for (int j = 0; j < 2; ++j) {
            bB[j][0] = *(const bf16x8*)(smem + bufS + bRow + (j + 2) * 1024 + c8_0);
            bB[j][1] = *(const bf16x8*)(smem + bufS + bRow + (j + 2) * 1024 + c8_1);
        }
        stage(srcA, nbufB, ktA);
        stage(srcA + 131072, nbufB + 16384, ktA);
        __builtin_amdgcn_s_setprio(1);
#pragma unroll
        for (int i = 0; i < 4; ++i)
#pragma unroll
            for (int j = 0; j < 2; ++j) {
                acc[i][j] = __builtin_amdgcn_mfma_f32_16x16x32_bf16(afL[i][0], bA[j][0], acc[i][j], 0, 0, 0);
                acc[i][j] = __builtin_amdgcn_mfma_f32_16x16x32_bf16(afL[i][1], bA[j][1], acc[i][j], 0, 0, 0);
            }
#pragma unroll
        for (int i = 0; i < 4; ++i)
#pragma unroll
            for (int j = 0; j < 2; ++j) {
                acc[i][j + 2] = __builtin_amdgcn_mfma_f32_16x16x32_bf16(afL[i][0], bB[j][0], acc[i][j + 2], 0, 0, 0);
                acc[i][j + 2] = __builtin_amdgcn_mfma_f32_16x16x32_bf16(afL[i][1], bB[j][1], acc[i][j + 2], 0, 0, 0);
            }
        __builtin_amdgcn_s_setprio(0);
        asm volatile("s_barrier" ::: "memory");

        bf16x8 afH[4][2];
#pragma unroll
        for (int i = 0; i < 4; ++i) {
            afH[i][0] = *(const bf16x8*)(smem + bufS + aRow + (i + 4) * 1024 + c8_0);
            afH[i][1] = *(const bf16x8*)(smem + bufS + aRow + (i + 4) * 1024 + c8_1);
        }
        stage(srcB, cbufB + 32768, ktB);
        stage(srcB + 131072, cbufB + 49152, ktB);
        __builtin_amdgcn_s_setprio(1);
#pragma unroll
        for (int i = 0; i < 4; ++i)
#pragma unroll
            for (int j = 0; j < 2; ++j) {
                acc[i + 4][j + 2] = __builtin_amdgcn_mfma_f32_16x16x32_bf16(afH[i][0], bB[j][0], acc[i + 4][j + 2], 0, 0, 0);
                acc[i + 4][j + 2] = __builtin_amdgcn_mfma_f32_16x16x32_bf16(afH[i][1], bB[j][1], acc[i + 4][j + 2], 0, 0, 0);
            }
#pragma unroll
        for (int i = 0; i < 4; ++i)
#pragma unroll
            for (int j = 0; j < 2; ++j) {
                acc[i + 4][j] = __builtin_amdgcn_mfma_f32_16x16x32_bf16(afH[i][0], bA[j][0], acc[i + 4][j], 0, 0, 0);
                acc[i + 4][j] = __builtin_amdgcn_mfma_f32_16x16x32_bf16(afH[i][1], bA[j][1], acc[i + 4][j], 0, 0, 0);
            }
        __builtin_amdgcn_s_setprio(0);
        asm volatile("s_waitcnt vmcnt(4)" ::: "memory");
        asm volatile("s_barrier" ::: "memory");
    }

    asm volatile("s_waitcnt vmcnt(0) lgkmcnt(0)" ::: "memory");
    asm volatile("s_barrier" ::: "memory");

    // ---- fp32 epilogue: 32-row quarters, stride-68 bounce, 16B stores -----
    float* epf = (float*)((char*)smem + wave * 16384);   // 16 KB per wave
#pragma unroll
    for (int hh = 0; hh < 4; ++hh) {
#pragma unroll
        for (int j = 0; j < 4; ++j) {
            const float bvv = bias[bn + wn + j * 16 + mr];
#pragma unroll
            for (int i2 = 0; i2 < 2; ++i2)
#pragma unroll
                for (int r = 0; r < 4; ++r)
                    epf[(i2 * 16 + quad * 4 + r) * 68 + j * 16 + mr] =
                        acc[hh * 2 + i2][j][r] + bvv;
        }
#pragma unroll
        for (int p = 0; p < 8; ++p) {
            const int row = p * 4 + (lane >> 4);
            const int ch = lane & 15;
            f32x4 v = *(const f32x4*)(epf + row * 68 + ch * 4);
            *(f32x4*)(Cf + (size_t)(bm + wm + hh * 32 + row) * 1024 + bn + wn + ch * 4) = v;
        }
    }
}

// ----------------- token-blocked wave attention (CHUNK = 4) ----------------
// QKV rows: (16384, 3072) bf16 = [q(1024) k(1024) v(1024)].
// 1 wave = 4 consecutive tokens; K/V rows s0-3..s0+6 streamed once each.
__global__ __launch_bounds__(256) void attn_wave4(
    const unsigned short* __restrict__ QKV, unsigned short* __restrict__ out) {
    const int lane = threadIdx.x & 63;
    const int wv   = threadIdx.x >> 6;
    const int id   = blockIdx.x;
    const int swz  = (id & 7) * 128 + (id >> 3);
    const int tok0 = swz * 16 + wv * 4;
    const int s0   = tok0 & 8191;
    const int bb   = tok0 - s0;
    const int le8  = lane * 8;

    const float NEG = -__builtin_inff();

    u16x8 qa[4][2];
#pragma unroll
    for (int t = 0; t < 4; ++t) {
        const size_t rq = (size_t)(tok0 + t) * 3072;
        qa[t][0] = *(const u16x8*)(QKV + rq + le8);
        qa[t][1] = *(const u16x8*)(QKV + rq + 512 + le8);
    }

    float sc0[4][7], sc1[4][7];
#pragma unroll
    for (int ri = 0; ri < 10; ++ri) {
        const int ks = s0 + ri - 3;
        const bool okr = (ks >= 0) & (ks < 8192);
        const int kc = ks < 0 ? 0 : (ks > 8191 ? 8191 : ks);
        const size_t kb = (size_t)(bb + kc) * 3072 + 1024;
        u16x8 k0 = *(const u16x8*)(QKV + kb + le8);
        u16x8 k1 = *(const u16x8*)(QKV + kb + 512 + le8);
#pragma unroll
        for (int t = 0; t < 4; ++t) {
            const int j = ri - t;
            if (j >= 0 && j < 7) {
                float d0 = 0.f, d1 = 0.f;
#pragma unroll
                for (int e = 0; e < 8; ++e) {
                    d0 += bf2f(qa[t][0][e]) * bf2f(k0[e]);
                    d1 += bf2f(qa[t][1][e]) * bf2f(k1[e]);
                }
#pragma unroll
                for (int off = 1; off <= 4; off <<= 1) {
                    d0 += __shfl_xor(d0, off);
                    d1 += __shfl_xor(d1, off);
                }
                sc0[t][j] = okr ? d0 * 0.125f : NEG;
                sc1[t][j] = okr ? d1 * 0.125f : NEG;
            }
        }
    }

    float w0[4][7], w1[4][7];
#pragma unroll
    for (int t = 0; t < 4; ++t) {
        float mx0 = sc0[t][0], mx1 = sc1[t][0];
#pragma unroll
        for (int j = 1; j < 7; ++j) { mx0 = fmaxf(mx0, sc0[t][j]); mx1 = fmaxf(mx1, sc1[t][j]); }
        float s0s = 0.f, s1s = 0.f;
#pragma unroll
        for (int j = 0; j < 7; ++j) {
            w0[t][j] = __builtin_amdgcn_exp2f((sc0[t][j] - mx0) * 1.44269504f);
            w1[t][j] = __builtin_amdgcn_exp2f((sc1[t][j] - mx1) * 1.44269504f);
            s0s += w0[t][j]; s1s += w1[t][j];
        }
        const float i0 = __builtin_amdgcn_rcpf(s0s);
        const float i1 = __builtin_amdgcn_rcpf(s1s);
#pragma unroll
        for (int j = 0; j < 7; ++j) { w0[t][j] *= i0; w1[t][j] *= i1; }
    }

    float o0[4][8] = {}, o1[4][8] = {};
#pragma unroll
    for (int ri = 0; ri < 10; ++ri) {
        const int ks = s0 + ri - 3;
        const int kc = ks < 0 ? 0 : (ks > 8191 ? 8191 : ks);
        const size_t vb = (size_t)(bb + kc) * 3072 + 2048;
        u16x8 v0 = *(const u16x8*)(QKV + vb + le8);
        u16x8 v1 = *(const u16x8*)(QKV + vb + 512 + le8);
        float vf0[8], vf1[8];
#pragma unroll
        for (int e = 0; e < 8; ++e) { vf0[e] = bf2f(v0[e]); vf1[e] = bf2f(v1[e]); }
#pragma unroll
        for (int t = 0; t < 4; ++t) {
            const int j = ri - t;
            if (j >= 0 && j < 7) {
#pragma unroll
                for (int e = 0; e < 8; ++e) {
                    o0[t][e] += w0[t][j] * vf0[e];
                    o1[t][e] += w1[t][j] * vf1[e];
                }
            }
        }
    }

#pragma unroll
    for (int t = 0; t < 4; ++t) {
        const size_t dst = (size_t)(tok0 + t) * 1024;
        u16x8 a, b2;
#pragma unroll
        for (int e = 0; e < 8; ++e) { a[e] = f2bf(o0[t][e]); b2[e] = f2bf(o1[t][e]); }
        *(u16x8*)(out + dst + le8) = a;
        *(u16x8*)(out + dst + 512 + le8) = b2;
    }
}

// ------------------------------- launch ------------------------------------
extern "C" void kernel_launch(void* const* d_in, const int* in_sizes, int n_in,
                              void* d_out, int out_size, void* d_ws, size_t ws_size,
                              hipStream_t stream) {
    (void)in_sizes; (void)n_in; (void)out_size; (void)ws_size;
    const float* X  = (const float*)d_in[0];
    const float* wq = (const float*)d_in[1];
    const float* bq = (const float*)d_in[2];
    const float* wk = (const float*)d_in[3];
    const float* bk = (const float*)d_in[4];
    const float* wv = (const float*)d_in[5];
    const float* bv = (const float*)d_in[6];
    const float* wo = (const float*)d_in[7];
    const float* bo = (const float*)d_in[8];
    float* out = (float*)d_out;

    char* ws = (char*)d_ws;
    unsigned short* Xb    = (unsigned short*)(ws);                 // 32 MB
    unsigned short* WtQKV = (unsigned short*)(ws + 33554432);      // 6 MB
    unsigned short* WtO   = (unsigned short*)(ws + 39845888);      // 2 MB
    unsigned short* QKV   = (unsigned short*)(ws + 41943040);      // 96 MB
    unsigned short* AttnO = (unsigned short*)(ws + 142606336);     // 32 MB
    float*          biasQ = (float*)(ws + 176160768);              // 12 KB

    prep<<<20492, 256, 0, stream>>>(X, wq, wk, wv, wo, bq, bk, bv,
                                    Xb, WtQKV, WtO, biasQ);

    // QKV: M=16384, N=3072, K=1024 -> unified QKV rows (256x256 tiles)
    gemm_qkv8<<<768, 512, 0, stream>>>(Xb, WtQKV, biasQ, QKV);

    // attention: 16384 tokens / 4 per wave = 4096 waves = 1024 blocks
    attn_wave4<<<1024, 256, 0, stream>>>(QKV, AttnO);

    // O-proj: M=16384, N=1024, K=1024, fp32 out (256x256 tiles, 256 blocks)
    gemm_out8<<<256, 512, 0, stream>>>(AttnO, WtO, bo, out);
}

// Round 9
// 316.512 us; speedup vs baseline: 1.0495x; 1.0027x over previous
//
#include <hip/hip_runtime.h>

// ---------------------------------------------------------------------------
// LigerFusedNeighborhoodAttention on MI355X (gfx950)
// B=2, S=8192, H=1024, NH=16, HD=64, KERNEL=7, DILATION=1, SCALE=1/8
//
// Pipeline (4 launches):
//   1. prep: cast X fp32->bf16 + transpose 4 weights + bias concat (fused)
//   2. fused QKV GEMM (16384 x 3072 x 1024): 256x256 tile, BK=64, 512 thr,
//      16x16x32 MFMA, read-ahead 2-barrier schedule (stage-issue-first),
//      counted vmcnt(4), setprio, XOR-swizzled LDS, XCD-bijective swizzle
//      -> unified row-major QKV (16384 x 3072)
//   3. token-blocked wave attention: 1 wave = 4 consecutive tokens; K/V rows
//      streamed once, register-reused; all loads 64-lane x 16B contiguous
//   4. output GEMM (16384 x 1024 x 1024): same 256x256 2-barrier schedule,
//      fp32 epilogue
// Round-6 verified configuration (312.5 us) + stage-issue-first micro-tweak.
// Rejected by measurement: 32x32 frags (9.4M bank conflicts, r7), cross-tile
// B reg-preload (scratch spills: WRITE_SIZE +9MB, r8).
// ---------------------------------------------------------------------------

typedef __bf16 bf16x8 __attribute__((ext_vector_type(8)));
typedef float f32x4 __attribute__((ext_vector_type(4)));
typedef int int4v __attribute__((ext_vector_type(4)));
typedef unsigned short u16x8 __attribute__((ext_vector_type(8)));
typedef __attribute__((address_space(1))) void as1_void;
typedef __attribute__((address_space(3))) void as3_void;

__device__ __forceinline__ float bf2f(unsigned short u) {
    union { unsigned int u; float f; } c;
    c.u = ((unsigned int)u) << 16;
    return c.f;
}
__device__ __forceinline__ unsigned short f2bf(float f) {
    union { float f; unsigned int u; } c;
    c.f = f;
    unsigned int u = c.u;
    u += 0x7fffu + ((u >> 16) & 1u);   // round-to-nearest-even
    return (unsigned short)(u >> 16);
}

// ------------- prep: cast X + transpose 4 weights + concat bias ------------
__global__ __launch_bounds__(256) void prep(
    const float* __restrict__ X, const float* __restrict__ w0,
    const float* __restrict__ w1, const float* __restrict__ w2,
    const float* __restrict__ w3, const float* __restrict__ bq,
    const float* __restrict__ bk, const float* __restrict__ bv,
    unsigned short* __restrict__ Xb, unsigned short* __restrict__ t0,
    unsigned short* __restrict__ t3, float* __restrict__ biasQ) {
    __shared__ unsigned short tile[32][33];
    const int bid = blockIdx.x;
    if (bid < 16384) {
        int i = bid * 256 + threadIdx.x;
        float4 v = ((const float4*)X)[i];
        ushort4 o;
        o.x = f2bf(v.x); o.y = f2bf(v.y); o.z = f2bf(v.z); o.w = f2bf(v.w);
        ((ushort4*)Xb)[i] = o;
    } else if (bid < 20480) {
        const int t = bid - 16384;
        const int z = t >> 10;
        const int rem = t & 1023;
        const float* W = (z == 0) ? w0 : (z == 1) ? w1 : (z == 2) ? w2 : w3;
        unsigned short* Wt = (z == 3) ? t3 : t0 + (size_t)z * 1048576;
        const int c0 = (rem & 31) * 32;
        const int r0 = (rem >> 5) * 32;
        const int tx = threadIdx.x & 31;
        const int ty = threadIdx.x >> 5;
#pragma unroll
        for (int i = 0; i < 32; i += 8)
            tile[ty + i][tx] = f2bf(W[(size_t)(r0 + ty + i) * 1024 + c0 + tx]);
        __syncthreads();
#pragma unroll
        for (int i = 0; i < 32; i += 8)
            Wt[(size_t)(c0 + ty + i) * 1024 + r0 + tx] = tile[tx][ty + i];
    } else {
        int i = (bid - 20480) * 256 + threadIdx.x;
        if (i < 3072)
            biasQ[i] = (i < 1024) ? bq[i] : ((i < 2048) ? bk[i - 1024] : bv[i - 2048]);
    }
}

// ---------------- QKV GEMM: 256x256 tile, 2-barrier schedule ---------------
// C(M,3072) = A(M,1024)*Bt(3072,1024)^T + bias -> unified QKV (stride 3072).
// 512 threads = 8 waves (2Mx4N), per-wave 128x64 = acc[8][4].
// LDS 128 KB: 2 dbuf x [A 32KB | B 32KB].  K=1024, BK=64, NT=16.
// Per K-tile (2 barriers):
//   half1: stage A(t+1)->other buf | ds_read afL+bA+bB | MFMA Q1,Q2 | BARRIER
//   half2: stage B(t+2)->current buf | ds_read afH | MFMA Q3,Q4 |
//          vmcnt(4) | BARRIER (buffer flip)
// Hazards: B(t+2) overwrites current-B only after mid barrier (reads consumed
// by Q1/Q2); afH reads current-A (nothing overwrites it this tile); vmcnt(4)
// leaves exactly B(t+2)'s 4 loads in flight.  Stage issued first in each
// half: disjoint regions, gives HBM latency a head start under ds_read+MFMA.
__global__ __launch_bounds__(512, 2) void gemm_qkv8(
    const unsigned short* __restrict__ A, const unsigned short* __restrict__ Bt,
    const float* __restrict__ bias, unsigned short* __restrict__ Cb) {
    constexpr int K = 1024;
    constexpr int NT = 16;                     // K / 64
    __shared__ unsigned short smem[65536];     // 128 KB
    const int tid  = threadIdx.x;
    const int lane = tid & 63;
    const int wave = tid >> 6;
    const int quad = lane >> 4;
    const int mr   = lane & 15;

    // XCD-bijective swizzle (768 blocks, 768 % 8 == 0)
    const int id  = blockIdx.x;
    const int swz = (id & 7) * 96 + (id >> 3);
    const int bm  = (swz / 12) * 256;
    const int bn  = (swz % 12) * 256;
    const int wm  = (wave >> 2) * 128;
    const int wn  = (wave & 3) * 64;

    const int r0 = tid >> 3;
    const int g8 = ((lane & 7) ^ ((lane >> 3) & 7)) * 8;
    const unsigned short* srcA = A  + (size_t)(bm + r0) * K + g8;
    const unsigned short* srcB = Bt + (size_t)(bn + r0) * K + g8;

    auto stage = [&](const unsigned short* gb, int ldsByte, int kt) {
#pragma unroll
        for (int l = 0; l < 2; ++l)
            __builtin_amdgcn_global_load_lds(
                (const as1_void*)(gb + (size_t)l * 65536 + kt),   // +64 rows
                (as3_void*)((char*)smem + ldsByte + l * 8192 + tid * 16),
                16, 0, 0);
    };

    // prologue: tile0 {A0,A1,B0,B1} -> buf0; tile1 {B0,B1} -> buf1
    stage(srcA,          0,     0);
    stage(srcA + 131072, 16384, 0);
    stage(srcB,          32768, 0);
    stage(srcB + 131072, 49152, 0);
    stage(srcB,          65536 + 32768, 64);
    stage(srcB + 131072, 65536 + 49152, 64);
    asm volatile("s_waitcnt vmcnt(4)" ::: "memory");   // tile0 landed; B(1) in flight
    asm volatile("s_barrier" ::: "memory");

    const int aRow = (wm + mr) * 64;            // shorts, within A region
    const int bRow = 16384 + (wn + mr) * 64;    // shorts, within B region
    const int c8_0 = ((0 * 4 + quad) ^ (mr & 7)) * 8;
    const int c8_1 = ((1 * 4 + quad) ^ (mr & 7)) * 8;

    f32x4 acc[8][4] = {};

    for (int t = 0; t < NT; ++t) {
        const int bufS  = (t & 1) << 15;           // current buf (shorts)
        const int nbufB = ((t + 1) & 1) << 16;     // next buf (bytes)
        const int cbufB = (t & 1) << 16;           // current buf (bytes)
        const int ktA = (t + 1 < NT ? t + 1 : NT - 1) * 64;
        const int ktB = (t + 2 < NT ? t + 2 : NT - 1) * 64;

        // ---- half 1: stage A(t+1) first; afL+bA+bB reads; MFMA Q1,Q2 ------
        stage(srcA, nbufB, ktA);
        stage(srcA + 131072, nbufB + 16384, ktA);
        bf16x8 afL[4][2], bA[2][2], bB[2][2];
#pragma unroll
        for (int i = 0; i < 4; ++i) {
            afL[i][0] = *(const bf16x8*)(smem + bufS + aRow + i * 1024 + c8_0);
            afL[i][1] = *(const bf16x8*)(smem + bufS + aRow + i * 1024 + c8_1);
        }
#pragma unroll
        for (int j = 0; j < 2; ++j) {
            bA[j][0] = *(const bf16x8*)(smem + bufS + bRow + j * 1024 + c8_0);
            bA[j][1] = *(const bf16x8*)(smem + bufS + bRow + j * 1024 + c8_1);
        }
#pragma unroll
        for (int j = 0; j < 2; ++j) {
            bB[j][0] = *(const bf16x8*)(smem + bufS + bRow + (j + 2) * 1024 + c8_0);
            bB[j][1] = *(const bf16x8*)(smem + bufS + bRow + (j + 2) * 1024 + c8_1);
        }
        __builtin_amdgcn_s_setprio(1);
#pragma unroll
        for (int i = 0; i < 4; ++i)
#pragma unroll
            for (int j = 0; j < 2; ++j) {
                acc[i][j] = __builtin_amdgcn_mfma_f32_16x16x32_bf16(afL[i][0], bA[j][0], acc[i][j], 0, 0, 0);
                acc[i][j] = __builtin_amdgcn_mfma_f32_16x16x32_bf16(afL[i][1], bA[j][1], acc[i][j], 0, 0, 0);
            }
#pragma unroll
        for (int i = 0; i < 4; ++i)
#pragma unroll
            for (int j = 0; j < 2; ++j) {
                acc[i][j + 2] = __builtin_amdgcn_mfma_f32_16x16x32_bf16(afL[i][0], bB[j][0], acc[i][j + 2], 0, 0, 0);
                acc[i][j + 2] = __builtin_amdgcn_mfma_f32_16x16x32_bf16(afL[i][1], bB[j][1], acc[i][j + 2], 0, 0, 0);
            }
        __builtin_amdgcn_s_setprio(0);
        asm volatile("s_barrier" ::: "memory");   // E_mid

        // ---- half 2: stage B(t+2) first; afH reads; MFMA Q3,Q4; vmcnt(4) --
        stage(srcB, cbufB + 32768, ktB);
        stage(srcB + 131072, cbufB + 49152, ktB);
        bf16x8 afH[4][2];
#pragma unroll
        for (int i = 0; i < 4; ++i) {
            afH[i][0] = *(const bf16x8*)(smem + bufS + aRow + (i + 4) * 1024 + c8_0);
            afH[i][1] = *(const bf16x8*)(smem + bufS + aRow + (i + 4) * 1024 + c8_1);
        }
        __builtin_amdgcn_s_setprio(1);
#pragma unroll
        for (int i = 0; i < 4; ++i)
#pragma unroll
            for (int j = 0; j < 2; ++j) {
                acc[i + 4][j + 2] = __builtin_amdgcn_mfma_f32_16x16x32_bf16(afH[i][0], bB[j][0], acc[i + 4][j + 2], 0, 0, 0);
                acc[i + 4][j + 2] = __builtin_amdgcn_mfma_f32_16x16x32_bf16(afH[i][1], bB[j][1], acc[i + 4][j + 2], 0, 0, 0);
            }
#pragma unroll
        for (int i = 0; i < 4; ++i)
#pragma unroll
            for (int j = 0; j < 2; ++j) {
                acc[i + 4][j] = __builtin_amdgcn_mfma_f32_16x16x32_bf16(afH[i][0], bA[j][0], acc[i + 4][j], 0, 0, 0);
                acc[i + 4][j] = __builtin_amdgcn_mfma_f32_16x16x32_bf16(afH[i][1], bA[j][1], acc[i + 4][j], 0, 0, 0);
            }
        __builtin_amdgcn_s_setprio(0);
        asm volatile("s_waitcnt vmcnt(4)" ::: "memory");   // tile t+1 fully landed
        asm volatile("s_barrier" ::: "memory");   // E_end
    }

    // drain all staging before reusing LDS as epilogue scratch
    asm volatile("s_waitcnt vmcnt(0) lgkmcnt(0)" ::: "memory");
    asm volatile("s_barrier" ::: "memory");

    // ------- epilogue (unified): bf16 rows, stride 3072, LDS bounce --------
    unsigned short* ep = smem + wave * 8192;   // 16 KB per wave
#pragma unroll
    for (int h = 0; h < 2; ++h) {
#pragma unroll
        for (int j = 0; j < 4; ++j) {
            const float bvv = bias[bn + wn + j * 16 + mr];
#pragma unroll
            for (int i = 0; i < 4; ++i)
#pragma unroll
                for (int r = 0; r < 4; ++r)
                    ep[(i * 16 + quad * 4 + r) * 68 + j * 16 + mr] =
                        f2bf(acc[h * 4 + i][j][r] + bvv);
        }
#pragma unroll
        for (int p = 0; p < 8; ++p) {
            const int row = p * 8 + (lane >> 3);
            const int gr = lane & 7;
            int4v v = *(const int4v*)(ep + row * 68 + gr * 8);
            *(int4v*)(Cb + (size_t)(bm + wm + h * 64 + row) * 3072 + bn + wn + gr * 8) = v;
        }
    }
}

// ------------- O-proj GEMM: same 256x256 2-barrier schedule, fp32 ----------
// C(16384,1024) = A(16384,1024)*Bt(1024,1024)^T + bias.  Grid 256 = 64x4.
__global__ __launch_bounds__(512, 2) void gemm_out8(
    const unsigned short* __restrict__ A, const unsigned short* __restrict__ Bt,
    const float* __restrict__ bias, float* __restrict__ Cf) {
    constexpr int K = 1024;
    constexpr int NT = 16;
    __shared__ unsigned short smem[65536];
    const int tid  = threadIdx.x;
    const int lane = tid & 63;
    const int wave = tid >> 6;
    const int quad = lane >> 4;
    const int mr   = lane & 15;

    // XCD-bijective swizzle (256 blocks, 256 % 8 == 0)
    const int id  = blockIdx.x;
    const int swz = (id & 7) * 32 + (id >> 3);
    const int bm  = (swz >> 2) * 256;
    const int bn  = (swz & 3) * 256;
    const int wm  = (wave >> 2) * 128;
    const int wn  = (wave & 3) * 64;

    const int r0 = tid >> 3;
    const int g8 = ((lane & 7) ^ ((lane >> 3) & 7)) * 8;
    const unsigned short* srcA = A  + (size_t)(bm + r0) * K + g8;
    const unsigned short* srcB = Bt + (size_t)(bn + r0) * K + g8;

    auto stage = [&](const unsigned short* gb, int ldsByte, int kt) {
#pragma unroll
        for (int l = 0; l < 2; ++l)
            __builtin_amdgcn_global_load_lds(
                (const as1_void*)(gb + (size_t)l * 65536 + kt),
                (as3_void*)((char*)smem + ldsByte + l * 8192 + tid * 16),
                16, 0, 0);
    };

    stage(srcA,          0,     0);
    stage(srcA + 131072, 16384, 0);
    stage(srcB,          32768, 0);
    stage(srcB + 131072, 49152, 0);
    stage(srcB,          65536 + 32768, 64);
    stage(srcB + 131072, 65536 + 49152, 64);
    asm volatile("s_waitcnt vmcnt(4)" ::: "memory");
    asm volatile("s_barrier" ::: "memory");

    const int aRow = (wm + mr) * 64;
    const int bRow = 16384 + (wn + mr) * 64;
    const int c8_0 = ((0 * 4 + quad) ^ (mr & 7)) * 8;
    const int c8_1 = ((1 * 4 + quad) ^ (mr & 7)) * 8;

    f32x4 acc[8][4] = {};

    for (int t = 0; t < NT; ++t) {
        const int bufS  = (t & 1) << 15;
        const int nbufB = ((t + 1) & 1) << 16;
        const int cbufB = (t & 1) << 16;
        const int ktA = (t + 1 < NT ? t + 1 : NT - 1) * 64;
        const int ktB = (t + 2 < NT ? t + 2 : NT - 1) * 64;

        // ---- half 1: stage A(t+1) first; afL+bA+bB reads; MFMA Q1,Q2 ------
        stage(srcA, nbufB, ktA);
        stage(srcA + 131072, nbufB + 16384, ktA);
        bf16x8 afL[4][2], bA[2][2], bB[2][2];
#pragma unroll
        for (int i = 0; i < 4; ++i) {
            afL[i][0] = *(const bf16x8*)(smem + bufS + aRow + i * 1024 + c8_0);
            afL[i][1] = *(const bf16x8*)(smem + bufS + aRow + i * 1024 + c8_1);
        }
#pragma unroll
        for (int j = 0; j < 2; ++j) {
            bA[j][0] = *(const bf16x8*)(smem + bufS + bRow + j * 1024 + c8_0);
            bA[j][1] = *(const bf16x8*)(smem + bufS + bRow + j * 1024 + c8_1);
        }
#pragma unroll
        for (int j = 0; j < 2; ++j) {
            bB[j][0] = *(const bf16x8*)(smem + bufS + bRow + (j + 2) * 1024 + c8_0);
            bB[j][1] = *(const bf16x8*)(smem + bufS + bRow + (j + 2) * 1024 + c8_1);
        }
        __builtin_amdgcn_s_setprio(1);
#pragma unroll
        for (int i = 0; i < 4; ++i)
#pragma unroll
            for (int j = 0; j < 2; ++j) {
                acc[i][j] = __builtin_amdgcn_mfma_f32_16x16x32_bf16(afL[i][0], bA[j][0], acc[i][j], 0, 0, 0);
                acc[i][j] = __builtin_amdgcn_mfma_f32_16x16x32_bf16(afL[i][1], bA[j][1], acc[i][j], 0, 0, 0);
            }
#pragma unroll
        for (int i = 0; i < 4; ++i)
#pragma unroll
            for (int j = 0; j < 2; ++j) {
                acc[i][j + 2] = __builtin_amdgcn_mfma_f32_16x16x32_bf16(afL[i][0], bB[j][0], acc[i][j + 2], 0, 0, 0);
                acc[i][j + 2] = __builtin_amdgcn_mfma_f32_16x16x32_bf16(afL[i][1], bB[j][1], acc[i][j + 2], 0, 0, 0);
            }
        __builtin_amdgcn_s_setprio(0);
        asm volatile("s_barrier" ::: "memory");

        // ---- half 2: stage B(t+2) first; afH reads; MFMA Q3,Q4; vmcnt(4) --
        stage(srcB, cbufB + 32768, ktB);
        stage(srcB + 131072, cbufB + 49152, ktB);
        bf16x8 afH[4][2];
#pragma unroll
        for (int i = 0; i < 4; ++i) {
            afH[i][0] = *(const bf16x8*)(smem + bufS + aRow + (i + 4) * 1024 + c8_0);
            afH[i][1] = *(const bf16x8*)(smem + bufS + aRow + (i + 4) * 1024 + c8_1);
        }
        __builtin_amdgcn_s_setprio(1);
#pragma unroll
        for (int i = 0; i < 4; ++i)
#pragma unroll
            for (int j = 0; j < 2; ++j) {
                acc[i + 4][j + 2] = __builtin_amdgcn_mfma_f32_16x16x32_bf16(afH[i][0], bB[j][0], acc[i + 4][j + 2], 0, 0, 0);
                acc[i + 4][j + 2] = __builtin_amdgcn_mfma_f32_16x16x32_bf16(afH[i][1], bB[j][1], acc[i + 4][j + 2], 0, 0, 0);
            }
#pragma unroll
        for (int i = 0; i < 4; ++i)
#pragma unroll
            for (int j = 0; j < 2; ++j) {
                acc[i + 4][j] = __builtin_amdgcn_mfma_f32_16x16x32_bf16(afH[i][0], bA[j][0], acc[i + 4][j], 0, 0, 0);
                acc[i + 4][j] = __builtin_amdgcn_mfma_f32_16x16x32_bf16(afH[i][1], bA[j][1], acc[i + 4][j], 0, 0, 0);
            }
        __builtin_amdgcn_s_setprio(0);
        asm volatile("s_waitcnt vmcnt(4)" ::: "memory");
        asm volatile("s_barrier" ::: "memory");
    }

    asm volatile("s_waitcnt vmcnt(0) lgkmcnt(0)" ::: "memory");
    asm volatile("s_barrier" ::: "memory");

    // ---- fp32 epilogue: 32-row quarters, stride-68 bounce, 16B stores -----
    float* epf = (float*)((char*)smem + wave * 16384);   // 16 KB per wave
#pragma unroll
    for (int hh = 0; hh < 4; ++hh) {
#pragma unroll
        for (int j = 0; j < 4; ++j) {
            const float bvv = bias[bn + wn + j * 16 + mr];
#pragma unroll
            for (int i2 = 0; i2 < 2; ++i2)
#pragma unroll
                for (int r = 0; r < 4; ++r)
                    epf[(i2 * 16 + quad * 4 + r) * 68 + j * 16 + mr] =
                        acc[hh * 2 + i2][j][r] + bvv;
        }
#pragma unroll
        for (int p = 0; p < 8; ++p) {
            const int row = p * 4 + (lane >> 4);
            const int ch = lane & 15;
            f32x4 v = *(const f32x4*)(epf + row * 68 + ch * 4);
            *(f32x4*)(Cf + (size_t)(bm + wm + hh * 32 + row) * 1024 + bn + wn + ch * 4) = v;
        }
    }
}

// ----------------- token-blocked wave attention (CHUNK = 4) ----------------
// QKV rows: (16384, 3072) bf16 = [q(1024) k(1024) v(1024)].
// 1 wave = 4 consecutive tokens; K/V rows s0-3..s0+6 streamed once each.
__global__ __launch_bounds__(256) void attn_wave4(
    const unsigned short* __restrict__ QKV, unsigned short* __restrict__ out) {
    const int lane = threadIdx.x & 63;
    const int wv   = threadIdx.x >> 6;
    const int id   = blockIdx.x;
    const int swz  = (id & 7) * 128 + (id >> 3);
    const int tok0 = swz * 16 + wv * 4;
    const int s0   = tok0 & 8191;
    const int bb   = tok0 - s0;
    const int le8  = lane * 8;

    const float NEG = -__builtin_inff();

    u16x8 qa[4][2];
#pragma unroll
    for (int t = 0; t < 4; ++t) {
        const size_t rq = (size_t)(tok0 + t) * 3072;
        qa[t][0] = *(const u16x8*)(QKV + rq + le8);
        qa[t][1] = *(const u16x8*)(QKV + rq + 512 + le8);
    }

    float sc0[4][7], sc1[4][7];
#pragma unroll
    for (int ri = 0; ri < 10; ++ri) {
        const int ks = s0 + ri - 3;
        const bool okr = (ks >= 0) & (ks < 8192);
        const int kc = ks < 0 ? 0 : (ks > 8191 ? 8191 : ks);
        const size_t kb = (size_t)(bb + kc) * 3072 + 1024;
        u16x8 k0 = *(const u16x8*)(QKV + kb + le8);
        u16x8 k1 = *(const u16x8*)(QKV + kb + 512 + le8);
#pragma unroll
        for (int t = 0; t < 4; ++t) {
            const int j = ri - t;
            if (j >= 0 && j < 7) {
                float d0 = 0.f, d1 = 0.f;
#pragma unroll
                for (int e = 0; e < 8; ++e) {
                    d0 += bf2f(qa[t][0][e]) * bf2f(k0[e]);
                    d1 += bf2f(qa[t][1][e]) * bf2f(k1[e]);
                }
#pragma unroll
                for (int off = 1; off <= 4; off <<= 1) {
                    d0 += __shfl_xor(d0, off);
                    d1 += __shfl_xor(d1, off);
                }
                sc0[t][j] = okr ? d0 * 0.125f : NEG;
                sc1[t][j] = okr ? d1 * 0.125f : NEG;
            }
        }
    }

    float w0[4][7], w1[4][7];
#pragma unroll
    for (int t = 0; t < 4; ++t) {
        float mx0 = sc0[t][0], mx1 = sc1[t][0];
#pragma unroll
        for (int j = 1; j < 7; ++j) { mx0 = fmaxf(mx0, sc0[t][j]); mx1 = fmaxf(mx1, sc1[t][j]); }
        float s0s = 0.f, s1s = 0.f;
#pragma unroll
        for (int j = 0; j < 7; ++j) {
            w0[t][j] = __builtin_amdgcn_exp2f((sc0[t][j] - mx0) * 1.44269504f);
            w1[t][j] = __builtin_amdgcn_exp2f((sc1[t][j] - mx1) * 1.44269504f);
            s0s += w0[t][j]; s1s += w1[t][j];
        }
        const float i0 = __builtin_amdgcn_rcpf(s0s);
        const float i1 = __builtin_amdgcn_rcpf(s1s);
#pragma unroll
        for (int j = 0; j < 7; ++j) { w0[t][j] *= i0; w1[t][j] *= i1; }
    }

    float o0[4][8] = {}, o1[4][8] = {};
#pragma unroll
    for (int ri = 0; ri < 10; ++ri) {
        const int ks = s0 + ri - 3;
        const int kc = ks < 0 ? 0 : (ks > 8191 ? 8191 : ks);
        const size_t vb = (size_t)(bb + kc) * 3072 + 2048;
        u16x8 v0 = *(const u16x8*)(QKV + vb + le8);
        u16x8 v1 = *(const u16x8*)(QKV + vb + 512 + le8);
        float vf0[8], vf1[8];
#pragma unroll
        for (int e = 0; e < 8; ++e) { vf0[e] = bf2f(v0[e]); vf1[e] = bf2f(v1[e]); }
#pragma unroll
        for (int t = 0; t < 4; ++t) {
            const int j = ri - t;
            if (j >= 0 && j < 7) {
#pragma unroll
                for (int e = 0; e < 8; ++e) {
                    o0[t][e] += w0[t][j] * vf0[e];
                    o1[t][e] += w1[t][j] * vf1[e];
                }
            }
        }
    }

#pragma unroll
    for (int t = 0; t < 4; ++t) {
        const size_t dst = (size_t)(tok0 + t) * 1024;
        u16x8 a, b2;
#pragma unroll
        for (int e = 0; e < 8; ++e) { a[e] = f2bf(o0[t][e]); b2[e] = f2bf(o1[t][e]); }
        *(u16x8*)(out + dst + le8) = a;
        *(u16x8*)(out + dst + 512 + le8) = b2;
    }
}

// ------------------------------- launch ------------------------------------
extern "C" void kernel_launch(void* const* d_in, const int* in_sizes, int n_in,
                              void* d_out, int out_size, void* d_ws, size_t ws_size,
                              hipStream_t stream) {
    (void)in_sizes; (void)n_in; (void)out_size; (void)ws_size;
    const float* X  = (const float*)d_in[0];
    const float* wq = (const float*)d_in[1];
    const float* bq = (const float*)d_in[2];
    const float* wk = (const float*)d_in[3];
    const float* bk = (const float*)d_in[4];
    const float* wv = (const float*)d_in[5];
    const float* bv = (const float*)d_in[6];
    const float* wo = (const float*)d_in[7];
    const float* bo = (const float*)d_in[8];
    float* out = (float*)d_out;

    char* ws = (char*)d_ws;
    unsigned short* Xb    = (unsigned short*)(ws);                 // 32 MB
    unsigned short* WtQKV = (unsigned short*)(ws + 33554432);      // 6 MB
    unsigned short* WtO   = (unsigned short*)(ws + 39845888);      // 2 MB
    unsigned short* QKV   = (unsigned short*)(ws + 41943040);      // 96 MB
    unsigned short* AttnO = (unsigned short*)(ws + 142606336);     // 32 MB
    float*          biasQ = (float*)(ws + 176160768);              // 12 KB

    prep<<<20492, 256, 0, stream>>>(X, wq, wk, wv, wo, bq, bk, bv,
                                    Xb, WtQKV, WtO, biasQ);

    // QKV: M=16384, N=3072, K=1024 -> unified QKV rows (256x256 tiles)
    gemm_qkv8<<<768, 512, 0, stream>>>(Xb, WtQKV, biasQ, QKV);

    // attention: 16384 tokens / 4 per wave = 4096 waves = 1024 blocks
    attn_wave4<<<1024, 256, 0, stream>>>(QKV, AttnO);

    // O-proj: M=16384, N=1024, K=1024, fp32 out (256x256 tiles, 256 blocks)
    gemm_out8<<<256, 512, 0, stream>>>(AttnO, WtO, bo, out);
}

// Round 10
// 309.230 us; speedup vs baseline: 1.0742x; 1.0235x over previous
//
#include <hip/hip_runtime.h>

// ---------------------------------------------------------------------------
// LigerFusedNeighborhoodAttention on MI355X (gfx950)
// B=2, S=8192, H=1024, NH=16, HD=64, KERNEL=7, DILATION=1, SCALE=1/8
//
// Pipeline (4 launches):
//   1. prep: cast X fp32->bf16 + transpose 4 weights + bias concat (fused)
//   2. fused QKV GEMM (16384 x 3072 x 1024): 256x256 tile, BK=64, 512 thr,
//      16x16x32 MFMA, read-ahead 2-barrier schedule, counted vmcnt(4),
//      setprio, XOR-swizzled LDS, XCD-bijective swizzle
//      -> unified row-major QKV (16384 x 3072)
//   3. token-blocked wave attention: 1 wave = 4 consecutive tokens; K/V rows
//      streamed once, register-reused; all loads 64-lane x 16B contiguous
//   4. output GEMM (16384 x 1024 x 1024): same 256x256 2-barrier schedule,
//      fp32 epilogue
// Round-6 verified optimum (312.5 us).  Rejected by measurement:
//   4-phase (r1: 127us), 32x32 frags (r7: 9.4M bank conflicts, 118us),
//   cross-tile B reg-preload (r8: scratch spills, 118us),
//   stage-issue-first (r9: 112us, null/negative).
// ---------------------------------------------------------------------------

typedef __bf16 bf16x8 __attribute__((ext_vector_type(8)));
typedef float f32x4 __attribute__((ext_vector_type(4)));
typedef int int4v __attribute__((ext_vector_type(4)));
typedef unsigned short u16x8 __attribute__((ext_vector_type(8)));
typedef __attribute__((address_space(1))) void as1_void;
typedef __attribute__((address_space(3))) void as3_void;

__device__ __forceinline__ float bf2f(unsigned short u) {
    union { unsigned int u; float f; } c;
    c.u = ((unsigned int)u) << 16;
    return c.f;
}
__device__ __forceinline__ unsigned short f2bf(float f) {
    union { float f; unsigned int u; } c;
    c.f = f;
    unsigned int u = c.u;
    u += 0x7fffu + ((u >> 16) & 1u);   // round-to-nearest-even
    return (unsigned short)(u >> 16);
}

// ------------- prep: cast X + transpose 4 weights + concat bias ------------
__global__ __launch_bounds__(256) void prep(
    const float* __restrict__ X, const float* __restrict__ w0,
    const float* __restrict__ w1, const float* __restrict__ w2,
    const float* __restrict__ w3, const float* __restrict__ bq,
    const float* __restrict__ bk, const float* __restrict__ bv,
    unsigned short* __restrict__ Xb, unsigned short* __restrict__ t0,
    unsigned short* __restrict__ t3, float* __restrict__ biasQ) {
    __shared__ unsigned short tile[32][33];
    const int bid = blockIdx.x;
    if (bid < 16384) {
        int i = bid * 256 + threadIdx.x;
        float4 v = ((const float4*)X)[i];
        ushort4 o;
        o.x = f2bf(v.x); o.y = f2bf(v.y); o.z = f2bf(v.z); o.w = f2bf(v.w);
        ((ushort4*)Xb)[i] = o;
    } else if (bid < 20480) {
        const int t = bid - 16384;
        const int z = t >> 10;
        const int rem = t & 1023;
        const float* W = (z == 0) ? w0 : (z == 1) ? w1 : (z == 2) ? w2 : w3;
        unsigned short* Wt = (z == 3) ? t3 : t0 + (size_t)z * 1048576;
        const int c0 = (rem & 31) * 32;
        const int r0 = (rem >> 5) * 32;
        const int tx = threadIdx.x & 31;
        const int ty = threadIdx.x >> 5;
#pragma unroll
        for (int i = 0; i < 32; i += 8)
            tile[ty + i][tx] = f2bf(W[(size_t)(r0 + ty + i) * 1024 + c0 + tx]);
        __syncthreads();
#pragma unroll
        for (int i = 0; i < 32; i += 8)
            Wt[(size_t)(c0 + ty + i) * 1024 + r0 + tx] = tile[tx][ty + i];
    } else {
        int i = (bid - 20480) * 256 + threadIdx.x;
        if (i < 3072)
            biasQ[i] = (i < 1024) ? bq[i] : ((i < 2048) ? bk[i - 1024] : bv[i - 2048]);
    }
}

// ---------------- QKV GEMM: 256x256 tile, 2-barrier schedule ---------------
// C(M,3072) = A(M,1024)*Bt(3072,1024)^T + bias -> unified QKV (stride 3072).
// 512 threads = 8 waves (2Mx4N), per-wave 128x64 = acc[8][4].
// LDS 128 KB: 2 dbuf x [A 32KB | B 32KB].  K=1024, BK=64, NT=16.
// Per K-tile (2 barriers only):
//   half1: ds_read afL+bA+bB | stage A(t+1)->other buf | MFMA Q1,Q2 | BARRIER
//   half2: ds_read afH | stage B(t+2)->current buf | MFMA Q3,Q4 |
//          vmcnt(4) | BARRIER (buffer flip)
// Hazards: B(t+2) overwrites current-B only after mid barrier (reads consumed
// by Q1/Q2); afH reads current-A (nothing overwrites it this tile); vmcnt(4)
// leaves exactly B(t+2)'s 4 loads in flight (8 issues/tile, in-order retire).
__global__ __launch_bounds__(512, 2) void gemm_qkv8(
    const unsigned short* __restrict__ A, const unsigned short* __restrict__ Bt,
    const float* __restrict__ bias, unsigned short* __restrict__ Cb) {
    constexpr int K = 1024;
    constexpr int NT = 16;                     // K / 64
    __shared__ unsigned short smem[65536];     // 128 KB
    const int tid  = threadIdx.x;
    const int lane = tid & 63;
    const int wave = tid >> 6;
    const int quad = lane >> 4;
    const int mr   = lane & 15;

    // XCD-bijective swizzle (768 blocks, 768 % 8 == 0)
    const int id  = blockIdx.x;
    const int swz = (id & 7) * 96 + (id >> 3);
    const int bm  = (swz / 12) * 256;
    const int bn  = (swz % 12) * 256;
    const int wm  = (wave >> 2) * 128;
    const int wn  = (wave & 3) * 64;

    const int r0 = tid >> 3;
    const int g8 = ((lane & 7) ^ ((lane >> 3) & 7)) * 8;
    const unsigned short* srcA = A  + (size_t)(bm + r0) * K + g8;
    const unsigned short* srcB = Bt + (size_t)(bn + r0) * K + g8;

    auto stage = [&](const unsigned short* gb, int ldsByte, int kt) {
#pragma unroll
        for (int l = 0; l < 2; ++l)
            __builtin_amdgcn_global_load_lds(
                (const as1_void*)(gb + (size_t)l * 65536 + kt),   // +64 rows
                (as3_void*)((char*)smem + ldsByte + l * 8192 + tid * 16),
                16, 0, 0);
    };

    // prologue: tile0 {A0,A1,B0,B1} -> buf0; tile1 {B0,B1} -> buf1
    stage(srcA,          0,     0);
    stage(srcA + 131072, 16384, 0);
    stage(srcB,          32768, 0);
    stage(srcB + 131072, 49152, 0);
    stage(srcB,          65536 + 32768, 64);
    stage(srcB + 131072, 65536 + 49152, 64);
    asm volatile("s_waitcnt vmcnt(4)" ::: "memory");   // tile0 landed; B(1) in flight
    asm volatile("s_barrier" ::: "memory");

    const int aRow = (wm + mr) * 64;            // shorts, within A region
    const int bRow = 16384 + (wn + mr) * 64;    // shorts, within B region
    const int c8_0 = ((0 * 4 + quad) ^ (mr & 7)) * 8;
    const int c8_1 = ((1 * 4 + quad) ^ (mr & 7)) * 8;

    f32x4 acc[8][4] = {};

    for (int t = 0; t < NT; ++t) {
        const int bufS  = (t & 1) << 15;           // current buf (shorts)
        const int nbufB = ((t + 1) & 1) << 16;     // next buf (bytes)
        const int cbufB = (t & 1) << 16;           // current buf (bytes)
        const int ktA = (t + 1 < NT ? t + 1 : NT - 1) * 64;
        const int ktB = (t + 2 < NT ? t + 2 : NT - 1) * 64;

        // ---- half 1: afL+bA+bB reads; stage A0+A1(t+1); MFMA Q1,Q2 --------
        bf16x8 afL[4][2], bA[2][2], bB[2][2];
#pragma unroll
        for (int i = 0; i < 4; ++i) {
            afL[i][0] = *(const bf16x8*)(smem + bufS + aRow + i * 1024 + c8_0);
            afL[i][1] = *(const bf16x8*)(smem + bufS + aRow + i * 1024 + c8_1);
        }
#pragma unroll
        for (int j = 0; j < 2; ++j) {
            bA[j][0] = *(const bf16x8*)(smem + bufS + bRow + j * 1024 + c8_0);
            bA[j][1] = *(const bf16x8*)(smem + bufS + bRow + j * 1024 + c8_1);
        }
#pragma unroll
        for (int j = 0; j < 2; ++j) {
            bB[j][0] = *(const bf16x8*)(smem + bufS + bRow + (j + 2) * 1024 + c8_0);
            bB[j][1] = *(const bf16x8*)(smem + bufS + bRow + (j + 2) * 1024 + c8_1);
        }
        stage(srcA, nbufB, ktA);
        stage(srcA + 131072, nbufB + 16384, ktA);
        __builtin_amdgcn_s_setprio(1);
#pragma unroll
        for (int i = 0; i < 4; ++i)
#pragma unroll
            for (int j = 0; j < 2; ++j) {
                acc[i][j] = __builtin_amdgcn_mfma_f32_16x16x32_bf16(afL[i][0], bA[j][0], acc[i][j], 0, 0, 0);
                acc[i][j] = __builtin_amdgcn_mfma_f32_16x16x32_bf16(afL[i][1], bA[j][1], acc[i][j], 0, 0, 0);
            }
#pragma unroll
        for (int i = 0; i < 4; ++i)
#pragma unroll
            for (int j = 0; j < 2; ++j) {
                acc[i][j + 2] = __builtin_amdgcn_mfma_f32_16x16x32_bf16(afL[i][0], bB[j][0], acc[i][j + 2], 0, 0, 0);
                acc[i][j + 2] = __builtin_amdgcn_mfma_f32_16x16x32_bf16(afL[i][1], bB[j][1], acc[i][j + 2], 0, 0, 0);
            }
        __builtin_amdgcn_s_setprio(0);
        asm volatile("s_barrier" ::: "memory");   // E_mid

        // ---- half 2: afH reads; stage B0+B1(t+2); MFMA Q3,Q4; vmcnt(4) ----
        bf16x8 afH[4][2];
#pragma unroll
        for (int i = 0; i < 4; ++i) {
            afH[i][0] = *(const bf16x8*)(smem + bufS + aRow + (i + 4) * 1024 + c8_0);
            afH[i][1] = *(const bf16x8*)(smem + bufS + aRow + (i + 4) * 1024 + c8_1);
        }
        stage(srcB, cbufB + 32768, ktB);
        stage(srcB + 131072, cbufB + 49152, ktB);
        __builtin_amdgcn_s_setprio(1);
#pragma unroll
        for (int i = 0; i < 4; ++i)
#pragma unroll
            for (int j = 0; j < 2; ++j) {
                acc[i + 4][j + 2] = __builtin_amdgcn_mfma_f32_16x16x32_bf16(afH[i][0], bB[j][0], acc[i + 4][j + 2], 0, 0, 0);
                acc[i + 4][j + 2] = __builtin_amdgcn_mfma_f32_16x16x32_bf16(afH[i][1], bB[j][1], acc[i + 4][j + 2], 0, 0, 0);
            }
#pragma unroll
        for (int i = 0; i < 4; ++i)
#pragma unroll
            for (int j = 0; j < 2; ++j) {
                acc[i + 4][j] = __builtin_amdgcn_mfma_f32_16x16x32_bf16(afH[i][0], bA[j][0], acc[i + 4][j], 0, 0, 0);
                acc[i + 4][j] = __builtin_amdgcn_mfma_f32_16x16x32_bf16(afH[i][1], bA[j][1], acc[i + 4][j], 0, 0, 0);
            }
        __builtin_amdgcn_s_setprio(0);
        asm volatile("s_waitcnt vmcnt(4)" ::: "memory");   // tile t+1 fully landed
        asm volatile("s_barrier" ::: "memory");   // E_end
    }

    // drain all staging before reusing LDS as epilogue scratch
    asm volatile("s_waitcnt vmcnt(0) lgkmcnt(0)" ::: "memory");
    asm volatile("s_barrier" ::: "memory");

    // ------- epilogue (unified): bf16 rows, stride 3072, LDS bounce --------
    unsigned short* ep = smem + wave * 8192;   // 16 KB per wave
#pragma unroll
    for (int h = 0; h < 2; ++h) {
#pragma unroll
        for (int j = 0; j < 4; ++j) {
            const float bvv = bias[bn + wn + j * 16 + mr];
#pragma unroll
            for (int i = 0; i < 4; ++i)
#pragma unroll
                for (int r = 0; r < 4; ++r)
                    ep[(i * 16 + quad * 4 + r) * 68 + j * 16 + mr] =
                        f2bf(acc[h * 4 + i][j][r] + bvv);
        }
#pragma unroll
        for (int p = 0; p < 8; ++p) {
            const int row = p * 8 + (lane >> 3);
            const int gr = lane & 7;
            int4v v = *(const int4v*)(ep + row * 68 + gr * 8);
            *(int4v*)(Cb + (size_t)(bm + wm + h * 64 + row) * 3072 + bn + wn + gr * 8) = v;
        }
    }
}

// ------------- O-proj GEMM: same 256x256 2-barrier schedule, fp32 ----------
// C(16384,1024) = A(16384,1024)*Bt(1024,1024)^T + bias.  Grid 256 = 64x4.
__global__ __launch_bounds__(512, 2) void gemm_out8(
    const unsigned short* __restrict__ A, const unsigned short* __restrict__ Bt,
    const float* __restrict__ bias, float* __restrict__ Cf) {
    constexpr int K = 1024;
    constexpr int NT = 16;
    __shared__ unsigned short smem[65536];
    const int tid  = threadIdx.x;
    const int lane = tid & 63;
    const int wave = tid >> 6;
    const int quad = lane >> 4;
    const int mr   = lane & 15;

    // XCD-bijective swizzle (256 blocks, 256 % 8 == 0)
    const int id  = blockIdx.x;
    const int swz = (id & 7) * 32 + (id >> 3);
    const int bm  = (swz >> 2) * 256;
    const int bn  = (swz & 3) * 256;
    const int wm  = (wave >> 2) * 128;
    const int wn  = (wave & 3) * 64;

    const int r0 = tid >> 3;
    const int g8 = ((lane & 7) ^ ((lane >> 3) & 7)) * 8;
    const unsigned short* srcA = A  + (size_t)(bm + r0) * K + g8;
    const unsigned short* srcB = Bt + (size_t)(bn + r0) * K + g8;

    auto stage = [&](const unsigned short* gb, int ldsByte, int kt) {
#pragma unroll
        for (int l = 0; l < 2; ++l)
            __builtin_amdgcn_global_load_lds(
                (const as1_void*)(gb + (size_t)l * 65536 + kt),
                (as3_void*)((char*)smem + ldsByte + l * 8192 + tid * 16),
                16, 0, 0);
    };

    stage(srcA,          0,     0);
    stage(srcA + 131072, 16384, 0);
    stage(srcB,          32768, 0);
    stage(srcB + 131072, 49152, 0);
    stage(srcB,          65536 + 32768, 64);
    stage(srcB + 131072, 65536 + 49152, 64);
    asm volatile("s_waitcnt vmcnt(4)" ::: "memory");
    asm volatile("s_barrier" ::: "memory");

    const int aRow = (wm + mr) * 64;
    const int bRow = 16384 + (wn + mr) * 64;
    const int c8_0 = ((0 * 4 + quad) ^ (mr & 7)) * 8;
    const int c8_1 = ((1 * 4 + quad) ^ (mr & 7)) * 8;

    f32x4 acc[8][4] = {};

    for (int t = 0; t < NT; ++t) {
        const int bufS  = (t & 1) << 15;
        const int nbufB = ((t + 1) & 1) << 16;
        const int cbufB = (t & 1) << 16;
        const int ktA = (t + 1 < NT ? t + 1 : NT - 1) * 64;
        const int ktB = (t + 2 < NT ? t + 2 : NT - 1) * 64;

        bf16x8 afL[4][2], bA[2][2], bB[2][2];
#pragma unroll
        for (int i = 0; i < 4; ++i) {
            afL[i][0] = *(const bf16x8*)(smem + bufS + aRow + i * 1024 + c8_0);
            afL[i][1] = *(const bf16x8*)(smem + bufS + aRow + i * 1024 + c8_1);
        }
#pragma unroll
        for (int j = 0; j < 2; ++j) {
            bA[j][0] = *(const bf16x8*)(smem + bufS + bRow + j * 1024 + c8_0);
            bA[j][1] = *(const bf16x8*)(smem + bufS + bRow + j * 1024 + c8_1);
        }
#pragma unroll
        for (int j = 0; j < 2; ++j) {
            bB[j][0] = *(const bf16x8*)(smem + bufS + bRow + (j + 2) * 1024 + c8_0);
            bB[j][1] = *(const bf16x8*)(smem + bufS + bRow + (j + 2) * 1024 + c8_1);
        }
        stage(srcA, nbufB, ktA);
        stage(srcA + 131072, nbufB + 16384, ktA);
        __builtin_amdgcn_s_setprio(1);
#pragma unroll
        for (int i = 0; i < 4; ++i)
#pragma unroll
            for (int j = 0; j < 2; ++j) {
                acc[i][j] = __builtin_amdgcn_mfma_f32_16x16x32_bf16(afL[i][0], bA[j][0], acc[i][j], 0, 0, 0);
                acc[i][j] = __builtin_amdgcn_mfma_f32_16x16x32_bf16(afL[i][1], bA[j][1], acc[i][j], 0, 0, 0);
            }
#pragma unroll
        for (int i = 0; i < 4; ++i)
#pragma unroll
            for (int j = 0; j < 2; ++j) {
                acc[i][j + 2] = __builtin_amdgcn_mfma_f32_16x16x32_bf16(afL[i][0], bB[j][0], acc[i][j + 2], 0, 0, 0);
                acc[i][j + 2] = __builtin_amdgcn_mfma_f32_16x16x32_bf16(afL[i][1], bB[j][1], acc[i][j + 2], 0, 0, 0);
            }
        __builtin_amdgcn_s_setprio(0);
        asm volatile("s_barrier" ::: "memory");

        bf16x8 afH[4][2];
#pragma unroll
        for (int i = 0; i < 4; ++i) {
            afH[i][0] = *(const bf16x8*)(smem + bufS + aRow + (i + 4) * 1024 + c8_0);
            afH[i][1] = *(const bf16x8*)(smem + bufS + aRow + (i + 4) * 1024 + c8_1);
        }
        stage(srcB, cbufB + 32768, ktB);
        stage(srcB + 131072, cbufB + 49152, ktB);
        __builtin_amdgcn_s_setprio(1);
#pragma unroll
        for (int i = 0; i < 4; ++i)
#pragma unroll
            for (int j = 0; j < 2; ++j) {
                acc[i + 4][j + 2] = __builtin_amdgcn_mfma_f32_16x16x32_bf16(afH[i][0], bB[j][0], acc[i + 4][j + 2], 0, 0, 0);
                acc[i + 4][j + 2] = __builtin_amdgcn_mfma_f32_16x16x32_bf16(afH[i][1], bB[j][1], acc[i + 4][j + 2], 0, 0, 0);
            }
#pragma unroll
        for (int i = 0; i < 4; ++i)
#pragma unroll
            for (int j = 0; j < 2; ++j) {
                acc[i + 4][j] = __builtin_amdgcn_mfma_f32_16x16x32_bf16(afH[i][0], bA[j][0], acc[i + 4][j], 0, 0, 0);
                acc[i + 4][j] = __builtin_amdgcn_mfma_f32_16x16x32_bf16(afH[i][1], bA[j][1], acc[i + 4][j], 0, 0, 0);
            }
        __builtin_amdgcn_s_setprio(0);
        asm volatile("s_waitcnt vmcnt(4)" ::: "memory");
        asm volatile("s_barrier" ::: "memory");
    }

    asm volatile("s_waitcnt vmcnt(0) lgkmcnt(0)" ::: "memory");
    asm volatile("s_barrier" ::: "memory");

    // ---- fp32 epilogue: 32-row quarters, stride-68 bounce, 16B stores -----
    float* epf = (float*)((char*)smem + wave * 16384);   // 16 KB per wave
#pragma unroll
    for (int hh = 0; hh < 4; ++hh) {
#pragma unroll
        for (int j = 0; j < 4; ++j) {
            const float bvv = bias[bn + wn + j * 16 + mr];
#pragma unroll
            for (int i2 = 0; i2 < 2; ++i2)
#pragma unroll
                for (int r = 0; r < 4; ++r)
                    epf[(i2 * 16 + quad * 4 + r) * 68 + j * 16 + mr] =
                        acc[hh * 2 + i2][j][r] + bvv;
        }
#pragma unroll
        for (int p = 0; p < 8; ++p) {
            const int row = p * 4 + (lane >> 4);
            const int ch = lane & 15;
            f32x4 v = *(const f32x4*)(epf + row * 68 + ch * 4);
            *(f32x4*)(Cf + (size_t)(bm + wm + hh * 32 + row) * 1024 + bn + wn + ch * 4) = v;
        }
    }
}

// ----------------- token-blocked wave attention (CHUNK = 4) ----------------
// QKV rows: (16384, 3072) bf16 = [q(1024) k(1024) v(1024)].
// 1 wave = 4 consecutive tokens; K/V rows s0-3..s0+6 streamed once each.
__global__ __launch_bounds__(256) void attn_wave4(
    const unsigned short* __restrict__ QKV, unsigned short* __restrict__ out) {
    const int lane = threadIdx.x & 63;
    const int wv   = threadIdx.x >> 6;
    const int id   = blockIdx.x;
    const int swz  = (id & 7) * 128 + (id >> 3);
    const int tok0 = swz * 16 + wv * 4;
    const int s0   = tok0 & 8191;
    const int bb   = tok0 - s0;
    const int le8  = lane * 8;

    const float NEG = -__builtin_inff();

    u16x8 qa[4][2];
#pragma unroll
    for (int t = 0; t < 4; ++t) {
        const size_t rq = (size_t)(tok0 + t) * 3072;
        qa[t][0] = *(const u16x8*)(QKV + rq + le8);
        qa[t][1] = *(const u16x8*)(QKV + rq + 512 + le8);
    }

    float sc0[4][7], sc1[4][7];
#pragma unroll
    for (int ri = 0; ri < 10; ++ri) {
        const int ks = s0 + ri - 3;
        const bool okr = (ks >= 0) & (ks < 8192);
        const int kc = ks < 0 ? 0 : (ks > 8191 ? 8191 : ks);
        const size_t kb = (size_t)(bb + kc) * 3072 + 1024;
        u16x8 k0 = *(const u16x8*)(QKV + kb + le8);
        u16x8 k1 = *(const u16x8*)(QKV + kb + 512 + le8);
#pragma unroll
        for (int t = 0; t < 4; ++t) {
            const int j = ri - t;
            if (j >= 0 && j < 7) {
                float d0 = 0.f, d1 = 0.f;
#pragma unroll
                for (int e = 0; e < 8; ++e) {
                    d0 += bf2f(qa[t][0][e]) * bf2f(k0[e]);
                    d1 += bf2f(qa[t][1][e]) * bf2f(k1[e]);
                }
#pragma unroll
                for (int off = 1; off <= 4; off <<= 1) {
                    d0 += __shfl_xor(d0, off);
                    d1 += __shfl_xor(d1, off);
                }
                sc0[t][j] = okr ? d0 * 0.125f : NEG;
                sc1[t][j] = okr ? d1 * 0.125f : NEG;
            }
        }
    }

    float w0[4][7], w1[4][7];
#pragma unroll
    for (int t = 0; t < 4; ++t) {
        float mx0 = sc0[t][0], mx1 = sc1[t][0];
#pragma unroll
        for (int j = 1; j < 7; ++j) { mx0 = fmaxf(mx0, sc0[t][j]); mx1 = fmaxf(mx1, sc1[t][j]); }
        float s0s = 0.f, s1s = 0.f;
#pragma unroll
        for (int j = 0; j < 7; ++j) {
            w0[t][j] = __builtin_amdgcn_exp2f((sc0[t][j] - mx0) * 1.44269504f);
            w1[t][j] = __builtin_amdgcn_exp2f((sc1[t][j] - mx1) * 1.44269504f);
            s0s += w0[t][j]; s1s += w1[t][j];
        }
        const float i0 = __builtin_amdgcn_rcpf(s0s);
        const float i1 = __builtin_amdgcn_rcpf(s1s);
#pragma unroll
        for (int j = 0; j < 7; ++j) { w0[t][j] *= i0; w1[t][j] *= i1; }
    }

    float o0[4][8] = {}, o1[4][8] = {};
#pragma unroll
    for (int ri = 0; ri < 10; ++ri) {
        const int ks = s0 + ri - 3;
        const int kc = ks < 0 ? 0 : (ks > 8191 ? 8191 : ks);
        const size_t vb = (size_t)(bb + kc) * 3072 + 2048;
        u16x8 v0 = *(const u16x8*)(QKV + vb + le8);
        u16x8 v1 = *(const u16x8*)(QKV + vb + 512 + le8);
        float vf0[8], vf1[8];
#pragma unroll
        for (int e = 0; e < 8; ++e) { vf0[e] = bf2f(v0[e]); vf1[e] = bf2f(v1[e]); }
#pragma unroll
        for (int t = 0; t < 4; ++t) {
            const int j = ri - t;
            if (j >= 0 && j < 7) {
#pragma unroll
                for (int e = 0; e < 8; ++e) {
                    o0[t][e] += w0[t][j] * vf0[e];
                    o1[t][e] += w1[t][j] * vf1[e];
                }
            }
        }
    }

#pragma unroll
    for (int t = 0; t < 4; ++t) {
        const size_t dst = (size_t)(tok0 + t) * 1024;
        u16x8 a, b2;
#pragma unroll
        for (int e = 0; e < 8; ++e) { a[e] = f2bf(o0[t][e]); b2[e] = f2bf(o1[t][e]); }
        *(u16x8*)(out + dst + le8) = a;
        *(u16x8*)(out + dst + 512 + le8) = b2;
    }
}

// ------------------------------- launch ------------------------------------
extern "C" void kernel_launch(void* const* d_in, const int* in_sizes, int n_in,
                              void* d_out, int out_size, void* d_ws, size_t ws_size,
                              hipStream_t stream) {
    (void)in_sizes; (void)n_in; (void)out_size; (void)ws_size;
    const float* X  = (const float*)d_in[0];
    const float* wq = (const float*)d_in[1];
    const float* bq = (const float*)d_in[2];
    const float* wk = (const float*)d_in[3];
    const float* bk = (const float*)d_in[4];
    const float* wv = (const float*)d_in[5];
    const float* bv = (const float*)d_in[6];
    const float* wo = (const float*)d_in[7];
    const float* bo = (const float*)d_in[8];
    float* out = (float*)d_out;

    char* ws = (char*)d_ws;
    unsigned short* Xb    = (unsigned short*)(ws);                 // 32 MB
    unsigned short* WtQKV = (unsigned short*)(ws + 33554432);      // 6 MB
    unsigned short* WtO   = (unsigned short*)(ws + 39845888);      // 2 MB
    unsigned short* QKV   = (unsigned short*)(ws + 41943040);      // 96 MB
    unsigned short* AttnO = (unsigned short*)(ws + 142606336);     // 32 MB
    float*          biasQ = (float*)(ws + 176160768);              // 12 KB

    prep<<<20492, 256, 0, stream>>>(X, wq, wk, wv, wo, bq, bk, bv,
                                    Xb, WtQKV, WtO, biasQ);

    // QKV: M=16384, N=3072, K=1024 -> unified QKV rows (256x256 tiles)
    gemm_qkv8<<<768, 512, 0, stream>>>(Xb, WtQKV, biasQ, QKV);

    // attention: 16384 tokens / 4 per wave = 4096 waves = 1024 blocks
    attn_wave4<<<1024, 256, 0, stream>>>(QKV, AttnO);

    // O-proj: M=16384, N=1024, K=1024, fp32 out (256x256 tiles, 256 blocks)
    gemm_out8<<<256, 512, 0, stream>>>(AttnO, WtO, bo, out);
}